// Round 2
// baseline (224.769 us; speedup 1.0000x reference)
//
#include <hip/hip_runtime.h>

#define NN 30000
#define NE 390000
#define HH 64
#define NGRAPH 64

#define EBLK 2048   // edge blocks in k_final
#define NBLK 1875   // node blocks in k_final (16 nodes each)

// ---------- sortable float encoding (ascending order preserved in uint) ----------
__device__ __forceinline__ unsigned sortable_f32(float f) {
    unsigned u = __float_as_uint(f);
    return (u & 0x80000000u) ? ~u : (u | 0x80000000u);
}
__device__ __forceinline__ float unsortable_f32(unsigned s) {
    unsigned u = (s & 0x80000000u) ? (s & 0x7fffffffu) : ~s;
    return __uint_as_float(u);
}

// tabs layout (float offsets):
// TV=0 (32x64), TC1=2048 (16x64), TC2=3072 (16x64), TC3=4096 (4x64),
// TQ=4352, TK=6400, TEK=8448 (each 32x64), TA=10496 (32x32), TB=11520 (32x32)
#define T_V   0
#define T_C1  2048
#define T_C2  3072
#define T_C3  4096
#define T_Q   4352
#define T_K   6400
#define T_EK  8448
#define T_A   10496
#define T_B   11520

__global__ void k_tab1(const float* __restrict__ emb_sbv, const float* __restrict__ emb_sbr,
                       const float* __restrict__ emb_edge, const float* __restrict__ emb_static,
                       const float* __restrict__ Wq, const float* __restrict__ Wk,
                       const float* __restrict__ Wv, const float* __restrict__ Wek,
                       const float* __restrict__ Wc, float* __restrict__ tabs) {
    int idx = blockIdx.x * 256 + threadIdx.x;
    if (idx >= 10496) return;
    float acc = 0.f;
    if (idx < 2048) {              // TV = emb_sbv @ Wv.T
        int r = idx >> 6, h = idx & 63;
        for (int j = 0; j < 64; ++j) acc += emb_sbv[r*64+j] * Wv[h*64+j];
        tabs[T_V + idx] = acc;
    } else if (idx < 3072) {       // TC1 = emb_edge @ Wc[:,0:64].T
        int t = idx - 2048; int r = t >> 6, h = t & 63;
        for (int j = 0; j < 64; ++j) acc += emb_edge[r*64+j] * Wc[h*192+j];
        tabs[T_C1 + t] = acc;
    } else if (idx < 4096) {       // TC2 = emb_edge @ Wc[:,64:128].T
        int t = idx - 3072; int r = t >> 6, h = t & 63;
        for (int j = 0; j < 64; ++j) acc += emb_edge[r*64+j] * Wc[h*192+64+j];
        tabs[T_C2 + t] = acc;
    } else if (idx < 4352) {       // TC3 = emb_static @ Wc[:,128:192].T
        int t = idx - 4096; int r = t >> 6, h = t & 63;
        for (int j = 0; j < 64; ++j) acc += emb_static[r*64+j] * Wc[h*192+128+j];
        tabs[T_C3 + t] = acc;
    } else if (idx < 6400) {       // TQ
        int t = idx - 4352; int r = t >> 6, h = t & 63;
        for (int j = 0; j < 64; ++j) acc += emb_sbv[r*64+j] * Wq[h*64+j];
        tabs[T_Q + t] = acc;
    } else if (idx < 8448) {       // TK
        int t = idx - 6400; int r = t >> 6, h = t & 63;
        for (int j = 0; j < 64; ++j) acc += emb_sbv[r*64+j] * Wk[h*64+j];
        tabs[T_K + t] = acc;
    } else {                       // TEK = emb_sbr @ Wek.T
        int t = idx - 8448; int r = t >> 6, h = t & 63;
        for (int j = 0; j < 64; ++j) acc += emb_sbr[r*64+j] * Wek[h*64+j];
        tabs[T_EK + t] = acc;
    }
}

__global__ void k_tab2(float* __restrict__ tabs) {
    int idx = blockIdx.x * 256 + threadIdx.x;
    if (idx >= 2048) return;
    const float* TQ = tabs + T_Q;
    float acc = 0.f;
    if (idx < 1024) {              // A[r1][r0] = TQ[r1]·TK[r0] / 8
        int r1 = idx >> 5, r0 = idx & 31;
        const float* TK = tabs + T_K;
        for (int j = 0; j < 64; ++j) acc += TQ[r1*64+j] * TK[r0*64+j];
        tabs[T_A + idx] = acc * 0.125f;
    } else {                       // B[r1][rk] = TQ[r1]·TEK[rk] / 8
        int t = idx - 1024; int r1 = t >> 5, rk = t & 31;
        const float* TEK = tabs + T_EK;
        for (int j = 0; j < 64; ++j) acc += TQ[r1*64+j] * TEK[rk*64+j];
        tabs[T_B + t] = acc * 0.125f;
    }
}

// per-node even state + node selection atomicMin
__global__ void k_node1(const int4* __restrict__ node_states, const float* __restrict__ scalars,
                        const int* __restrict__ batch_vec, int* __restrict__ ns,
                        unsigned long long* __restrict__ nodeSel) {
    int i = blockIdx.x * 256 + threadIdx.x;
    if (i >= NN) return;
    int4 b = node_states[i];
    int st = 2 * (b.x + 2*b.y + 4*b.z + 8*b.w);
    ns[i] = st;
    int key = (st >> 1) * NGRAPH + batch_vec[i];
    unsigned long long pk = ((unsigned long long)sortable_f32(scalars[i]) << 32) | (unsigned)i;
    atomicMin(&nodeSel[key], pk);
}

__global__ void k_node2(const int* __restrict__ ns, const int* __restrict__ batch_vec,
                        const unsigned long long* __restrict__ nodeSel, int* __restrict__ row) {
    int i = blockIdx.x * 256 + threadIdx.x;
    if (i >= NN) return;
    int st = ns[i];
    int key = (st >> 1) * NGRAPH + batch_vec[i];
    unsigned win = (unsigned)(nodeSel[key] & 0xffffffffull);
    row[i] = st + (win == (unsigned)i ? 1 : 0);
}

// per-edge: static feature idx, edge-state idx, edge selection atomicMin
__global__ void k_edge1(const int4* __restrict__ edge_states, const float* __restrict__ scalars,
                        const int* __restrict__ ei0, const int* __restrict__ ei1,
                        const int* __restrict__ ns, unsigned char* __restrict__ esi,
                        unsigned long long* __restrict__ edgeSel) {
    int e = blockIdx.x * 256 + threadIdx.x;
    if (e >= NE) return;
    int4 b = edge_states[e];
    int es = b.x + 2*b.y + 4*b.z + 8*b.w;
    float sc = scalars[e];
    int s0 = ei0[e], s1 = ei1[e];
    float send = scalars[s0], recv = scalars[s1];
    int si = (sc < recv ? 1 : 0) + (send + sc < recv ? 2 : 0);
    esi[e] = (unsigned char)(es | (si << 4));
    int st = ns[s0];
    int key = (st >> 1) * NN + s1;
    unsigned long long pk = ((unsigned long long)sortable_f32(sc) << 32) | (unsigned)e;
    atomicMin(&edgeSel[key], pk);
}

// per-edge: alpha from A/B tables, running segment max, pack info (incl s1)
__global__ void k_edge2(const int* __restrict__ ei0, const int* __restrict__ ei1,
                        const int* __restrict__ ns, const int* __restrict__ row,
                        const unsigned long long* __restrict__ edgeSel,
                        const unsigned char* __restrict__ esi, const int* __restrict__ rev_idx,
                        const float* __restrict__ tabs, float* __restrict__ alphaArr,
                        unsigned* __restrict__ einfo, unsigned* __restrict__ mArr) {
    int e = blockIdx.x * 256 + threadIdx.x;
    if (e >= NE) return;
    int s0 = ei0[e], s1 = ei1[e];
    int st = ns[s0];
    int key = (st >> 1) * NN + s1;
    unsigned win = (unsigned)(edgeSel[key] & 0xffffffffull);
    int ekrow = st + (win == (unsigned)e ? 1 : 0);
    int r0 = row[s0], r1 = row[s1];
    float alpha = tabs[T_A + r1*32 + r0] + tabs[T_B + r1*32 + ekrow];
    alphaArr[e] = alpha;
    atomicMax(&mArr[s1], sortable_f32(alpha));
    unsigned inf = esi[e];
    unsigned infr = esi[rev_idx[e]];
    einfo[e] = (unsigned)r0 | ((inf & 15u) << 5) | ((infr & 15u) << 9) | ((inf >> 4) << 13)
             | ((unsigned)s1 << 15);
}

// per-edge: exp, segment sum, and (fast path) 4 scalar weight atomics
__global__ void k_edge3(const unsigned* __restrict__ einfo, const unsigned* __restrict__ mArr,
                        const int* __restrict__ step_ptr, float* __restrict__ alphaArr,
                        float* __restrict__ ssum,
                        float* __restrict__ wTV, float* __restrict__ wC1,
                        float* __restrict__ wC2, float* __restrict__ wC3) {
    int e = blockIdx.x * 256 + threadIdx.x;
    if (e >= NE) return;
    int step = step_ptr[0];
    float tau;
    if (step == -1) tau = 1.0f;
    else { float frac = fminf((float)step / 10000.f, 1.f); tau = 3.0f + (0.1f - 3.0f) * frac; }
    unsigned info = einfo[e];
    int s1 = (info >> 15) & 32767;
    float m = unsortable_f32(mArr[s1]);
    float ex = expf((alphaArr[e] - m) / tau);
    alphaArr[e] = ex;
    unsafeAtomicAdd(&ssum[s1], ex);
    if (wTV) {
        unsafeAtomicAdd(&wTV[s1*32 + (info & 31)], ex);
        unsafeAtomicAdd(&wC1[s1*16 + ((info >> 5) & 15)], ex);
        unsafeAtomicAdd(&wC2[s1*16 + ((info >> 9) & 15)], ex);
        unsafeAtomicAdd(&wC3[s1*4 + ((info >> 13) & 3)], ex);
    }
}

// FAST PATH final: edge blocks write edge_out (pure float4 stores);
// node blocks compose node_out from per-node weights. No output atomics.
__global__ __launch_bounds__(256) void k_final(
        const unsigned* __restrict__ einfo, const float* __restrict__ exArr,
        const float* __restrict__ ssum, const int* __restrict__ rowArr,
        const float* __restrict__ tabs, const float* __restrict__ emb_edge,
        const float* __restrict__ emb_sbv,
        const float* __restrict__ wTV, const float* __restrict__ wC1,
        const float* __restrict__ wC2, const float* __restrict__ wC3,
        float* __restrict__ out_node, float* __restrict__ out_edge) {
    __shared__ float lds[5376];
    int tid = threadIdx.x;
    if (blockIdx.x < EBLK) {
        for (int j = tid; j < 4352; j += 256) lds[j] = tabs[j];
        for (int j = tid; j < 1024; j += 256) lds[4352 + j] = emb_edge[j];
        __syncthreads();
        int lane = tid & 63;
        int q = lane >> 4, c4 = (lane & 15) << 2;
        int wid = (blockIdx.x * 256 + tid) >> 6;
        const int NQ = NE / 4;
        for (int quad = wid; quad < NQ; quad += EBLK * 4) {
            int e = (quad << 2) + q;
            unsigned info = einfo[e];
            float ex = exArr[e];
            int s1 = (info >> 15) & 32767;
            float p = ex / ssum[s1];
            int r0 = info & 31;
            int es  = (info >> 5) & 15;
            int esr = (info >> 9) & 15;
            int si  = (info >> 13) & 3;
            const float4 tv = *(const float4*)&lds[(r0 << 6) + c4];
            const float4 c1 = *(const float4*)&lds[2048 + (es << 6) + c4];
            const float4 c2 = *(const float4*)&lds[3072 + (esr << 6) + c4];
            const float4 c3 = *(const float4*)&lds[4096 + (si << 6) + c4];
            const float4 ee = *(const float4*)&lds[4352 + (es << 6) + c4];
            float4 o;
            o.x = ee.x + p * (tv.x + c1.x + c2.x + c3.x);
            o.y = ee.y + p * (tv.y + c1.y + c2.y + c3.y);
            o.z = ee.z + p * (tv.z + c1.z + c2.z + c3.z);
            o.w = ee.w + p * (tv.w + c1.w + c2.w + c3.w);
            *(float4*)&out_edge[(size_t)e * 64 + c4] = o;
        }
    } else {
        for (int j = tid; j < 4352; j += 256) lds[j] = tabs[j];
        __syncthreads();
        int b = blockIdx.x - EBLK;
        int w = tid >> 6, l = tid & 63;
        int ibase = b * 16 + w * 4;
        for (int k = 0; k < 4; ++k) {
            int i = ibase + k;
            float inv = 1.f / ssum[i];
            float acc = emb_sbv[(rowArr[i] << 6) + l];
            float s = 0.f;
            const float* wv = wTV + i * 32;
            #pragma unroll
            for (int r = 0; r < 32; ++r) s += wv[r] * lds[(r << 6) + l];
            const float* w1 = wC1 + i * 16;
            #pragma unroll
            for (int r = 0; r < 16; ++r) s += w1[r] * lds[2048 + (r << 6) + l];
            const float* w2 = wC2 + i * 16;
            #pragma unroll
            for (int r = 0; r < 16; ++r) s += w2[r] * lds[3072 + (r << 6) + l];
            const float* w3 = wC3 + i * 4;
            #pragma unroll
            for (int r = 0; r < 4; ++r) s += w3[r] * lds[4096 + (r << 6) + l];
            out_node[(size_t)(i << 6) + l] = acc + s * inv;
        }
    }
}

// ---------- FALLBACK path (small ws): round-1 style ----------
__global__ void k_node3(const int* __restrict__ row, const float* __restrict__ emb_sbv,
                        float* __restrict__ out_node) {
    int t = blockIdx.x * 256 + threadIdx.x;
    if (t >= NN * HH) return;
    int i = t >> 6, h = t & 63;
    out_node[t] = emb_sbv[row[i]*64 + h];
}

__global__ __launch_bounds__(256) void k_edge4_atomic(
        const unsigned* __restrict__ einfo, const float* __restrict__ exArr,
        const float* __restrict__ ssum, const float* __restrict__ tabs,
        const float* __restrict__ emb_edge, float* __restrict__ out_node,
        float* __restrict__ out_edge) {
    __shared__ float lds[5376];
    int tid = threadIdx.x;
    for (int j = tid; j < 4352; j += 256) lds[j] = tabs[j];
    for (int j = tid; j < 1024; j += 256) lds[4352 + j] = emb_edge[j];
    __syncthreads();
    int lane = tid & 63;
    int wv = (blockIdx.x * 256 + tid) >> 6;
    int nw = (gridDim.x * 256) >> 6;
    for (int e = wv; e < NE; e += nw) {
        unsigned info = einfo[e];
        int s1 = (info >> 15) & 32767;
        float p = exArr[e] / ssum[s1];
        int r0 = info & 31;
        int es  = (info >> 5) & 15;
        int esr = (info >> 9) & 15;
        int si  = (info >> 13) & 3;
        float msg = p * (lds[r0*64 + lane] + lds[2048 + es*64 + lane]
                       + lds[3072 + esr*64 + lane] + lds[4096 + si*64 + lane]);
        out_edge[(size_t)e * 64 + lane] = lds[4352 + es*64 + lane] + msg;
        unsafeAtomicAdd(&out_node[(size_t)s1 * 64 + lane], msg);
    }
}

extern "C" void kernel_launch(void* const* d_in, const int* in_sizes, int n_in,
                              void* d_out, int out_size, void* d_ws, size_t ws_size,
                              hipStream_t stream) {
    const int4*  node_states = (const int4*)d_in[0];
    const int4*  edge_states = (const int4*)d_in[1];
    const float* scalars     = (const float*)d_in[2];
    const int*   edge_index  = (const int*)d_in[3];
    const int*   batch_vec   = (const int*)d_in[4];
    const int*   rev_idx     = (const int*)d_in[5];
    const float* emb_edge    = (const float*)d_in[6];
    const float* emb_sbv     = (const float*)d_in[7];
    const float* emb_sbr     = (const float*)d_in[8];
    const float* emb_static  = (const float*)d_in[9];
    const float* Wq  = (const float*)d_in[10];
    const float* Wk  = (const float*)d_in[11];
    const float* Wv  = (const float*)d_in[12];
    const float* Wek = (const float*)d_in[13];
    const float* Wc  = (const float*)d_in[15];
    const int*   step = (const int*)d_in[16];

    const int* ei0 = edge_index;
    const int* ei1 = edge_index + NE;

    char* ws = (char*)d_ws;
    // layout (byte offsets):
    // [0, 3,840,000)           edgeSel u64 16*NN   -> later wTV f32 NN*32
    // [3,840,000, 4,230,000)   esi u8 NE           -> later wC3 f32 NN*4 spills into ns
    // [4,230,000, 4,350,000)   ns i32 NN
    // [4,350,000, 4,358,192)   nodeSel u64 1024
    // [4,358,192, 4,478,192)   mArr u32 NN
    // [4,478,192, 4,598,192)   rowArr i32 NN
    // [4,598,192, 6,158,192)   alpha/ex f32 NE
    // [6,158,192, 7,718,192)   einfo u32 NE
    // [7,718,192, 7,838,192)   ssum f32 NN
    // fast:  [7,838,192, 9,758,192) wC1; [9,758,192, 11,678,192) wC2; [11,678,192, +50,176) tabs
    // fallback: [7,838,192, +50,176) tabs
    unsigned long long* edgeSel = (unsigned long long*)(ws);
    unsigned char* esi = (unsigned char*)(ws + 3840000);
    int*      ns     = (int*)(ws + 4230000);
    unsigned long long* nodeSel = (unsigned long long*)(ws + 4350000);
    unsigned* mArr   = (unsigned*)(ws + 4358192);
    int*      rowArr = (int*)(ws + 4478192);
    float*    alphaArr = (float*)(ws + 4598192);
    unsigned* einfo  = (unsigned*)(ws + 6158192);
    float*    ssum   = (float*)(ws + 7718192);

    bool fast = (ws_size >= 11728368ull);
    float* wTV = fast ? (float*)(ws) : nullptr;                 // aliases edgeSel (dead by then)
    float* wC3 = fast ? (float*)(ws + 3840000) : nullptr;       // aliases esi/ns (dead by then)
    float* wC1 = fast ? (float*)(ws + 7838192) : nullptr;
    float* wC2 = fast ? (float*)(ws + 9758192) : nullptr;
    float* tabs = fast ? (float*)(ws + 11678192) : (float*)(ws + 7838192);

    float* out_node = (float*)d_out;
    float* out_edge = out_node + (size_t)NN * HH;

    // init: selection slots to 0xFF (max), mArr/ssum (+weights) to 0
    hipMemsetAsync(ws, 0xFF, 4358192, stream);                  // edgeSel..nodeSel
    hipMemsetAsync(ws + 4358192, 0, 120000, stream);            // mArr
    if (fast) hipMemsetAsync(ws + 7718192, 0, 3960000, stream); // ssum + wC1 + wC2
    else      hipMemsetAsync(ws + 7718192, 0, 120000, stream);  // ssum

    hipLaunchKernelGGL(k_tab1, dim3(41), dim3(256), 0, stream,
                       emb_sbv, emb_sbr, emb_edge, emb_static, Wq, Wk, Wv, Wek, Wc, tabs);
    hipLaunchKernelGGL(k_tab2, dim3(8), dim3(256), 0, stream, tabs);

    int nb_node = (NN + 255) / 256;
    int nb_edge = (NE + 255) / 256;

    hipLaunchKernelGGL(k_node1, dim3(nb_node), dim3(256), 0, stream,
                       node_states, scalars, batch_vec, ns, nodeSel);
    hipLaunchKernelGGL(k_edge1, dim3(nb_edge), dim3(256), 0, stream,
                       edge_states, scalars, ei0, ei1, ns, esi, edgeSel);
    hipLaunchKernelGGL(k_node2, dim3(nb_node), dim3(256), 0, stream,
                       ns, batch_vec, nodeSel, rowArr);
    hipLaunchKernelGGL(k_edge2, dim3(nb_edge), dim3(256), 0, stream,
                       ei0, ei1, ns, rowArr, edgeSel, esi, rev_idx, tabs, alphaArr, einfo, mArr);
    if (fast) hipMemsetAsync(ws, 0, 4320000, stream);           // zero wTV + wC3 (edgeSel/esi/ns now dead)
    hipLaunchKernelGGL(k_edge3, dim3(nb_edge), dim3(256), 0, stream,
                       einfo, mArr, step, alphaArr, ssum, wTV, wC1, wC2, wC3);
    if (fast) {
        hipLaunchKernelGGL(k_final, dim3(EBLK + NBLK), dim3(256), 0, stream,
                           einfo, alphaArr, ssum, rowArr, tabs, emb_edge, emb_sbv,
                           wTV, wC1, wC2, wC3, out_node, out_edge);
    } else {
        hipLaunchKernelGGL(k_node3, dim3((NN * HH + 255) / 256), dim3(256), 0, stream,
                           rowArr, emb_sbv, out_node);
        hipLaunchKernelGGL(k_edge4_atomic, dim3(2048), dim3(256), 0, stream,
                           einfo, alphaArr, ssum, tabs, emb_edge, out_node, out_edge);
    }
}

// Round 3
// 179.199 us; speedup vs baseline: 1.2543x; 1.2543x over previous
//
#include <hip/hip_runtime.h>

#define NN 30000
#define NE 390000
#define HH 64
#define NGRAPH 64

// ---------- sortable float encoding (ascending order preserved in uint) ----------
__device__ __forceinline__ unsigned sortable_f32(float f) {
    unsigned u = __float_as_uint(f);
    return (u & 0x80000000u) ? ~u : (u | 0x80000000u);
}

// tabs layout (float offsets):
// TV=0 (32x64), TC1=2048 (16x64), TC2=3072 (16x64), TC3=4096 (4x64),
// TQ=4352, TK=6400, TEK=8448 (each 32x64), TA=10496 (32x32), TB=11520 (32x32)
#define T_V   0
#define T_C1  2048
#define T_C2  3072
#define T_C3  4096
#define T_Q   4352
#define T_K   6400
#define T_EK  8448
#define T_A   10496
#define T_B   11520

__global__ void k_tab1(const float* __restrict__ emb_sbv, const float* __restrict__ emb_sbr,
                       const float* __restrict__ emb_edge, const float* __restrict__ emb_static,
                       const float* __restrict__ Wq, const float* __restrict__ Wk,
                       const float* __restrict__ Wv, const float* __restrict__ Wek,
                       const float* __restrict__ Wc, float* __restrict__ tabs) {
    int idx = blockIdx.x * 256 + threadIdx.x;
    if (idx >= 10496) return;
    float acc = 0.f;
    if (idx < 2048) {              // TV = emb_sbv @ Wv.T
        int r = idx >> 6, h = idx & 63;
        for (int j = 0; j < 64; ++j) acc += emb_sbv[r*64+j] * Wv[h*64+j];
        tabs[T_V + idx] = acc;
    } else if (idx < 3072) {       // TC1 = emb_edge @ Wc[:,0:64].T
        int t = idx - 2048; int r = t >> 6, h = t & 63;
        for (int j = 0; j < 64; ++j) acc += emb_edge[r*64+j] * Wc[h*192+j];
        tabs[T_C1 + t] = acc;
    } else if (idx < 4096) {       // TC2 = emb_edge @ Wc[:,64:128].T
        int t = idx - 3072; int r = t >> 6, h = t & 63;
        for (int j = 0; j < 64; ++j) acc += emb_edge[r*64+j] * Wc[h*192+64+j];
        tabs[T_C2 + t] = acc;
    } else if (idx < 4352) {       // TC3 = emb_static @ Wc[:,128:192].T
        int t = idx - 4096; int r = t >> 6, h = t & 63;
        for (int j = 0; j < 64; ++j) acc += emb_static[r*64+j] * Wc[h*192+128+j];
        tabs[T_C3 + t] = acc;
    } else if (idx < 6400) {       // TQ
        int t = idx - 4352; int r = t >> 6, h = t & 63;
        for (int j = 0; j < 64; ++j) acc += emb_sbv[r*64+j] * Wq[h*64+j];
        tabs[T_Q + t] = acc;
    } else if (idx < 8448) {       // TK
        int t = idx - 6400; int r = t >> 6, h = t & 63;
        for (int j = 0; j < 64; ++j) acc += emb_sbv[r*64+j] * Wk[h*64+j];
        tabs[T_K + t] = acc;
    } else {                       // TEK = emb_sbr @ Wek.T
        int t = idx - 8448; int r = t >> 6, h = t & 63;
        for (int j = 0; j < 64; ++j) acc += emb_sbr[r*64+j] * Wek[h*64+j];
        tabs[T_EK + t] = acc;
    }
}

__global__ void k_tab2(float* __restrict__ tabs) {
    int idx = blockIdx.x * 256 + threadIdx.x;
    if (idx >= 2048) return;
    const float* TQ = tabs + T_Q;
    float acc = 0.f;
    if (idx < 1024) {              // A[r1][r0] = TQ[r1]·TK[r0] / 8
        int r1 = idx >> 5, r0 = idx & 31;
        const float* TK = tabs + T_K;
        for (int j = 0; j < 64; ++j) acc += TQ[r1*64+j] * TK[r0*64+j];
        tabs[T_A + idx] = acc * 0.125f;
    } else {                       // B[r1][rk] = TQ[r1]·TEK[rk] / 8
        int t = idx - 1024; int r1 = t >> 5, rk = t & 31;
        const float* TEK = tabs + T_EK;
        for (int j = 0; j < 64; ++j) acc += TQ[r1*64+j] * TEK[rk*64+j];
        tabs[T_B + t] = acc * 0.125f;
    }
}

// per-node even state + node selection atomicMin
__global__ void k_node1(const int4* __restrict__ node_states, const float* __restrict__ scalars,
                        const int* __restrict__ batch_vec, int* __restrict__ ns,
                        unsigned long long* __restrict__ nodeSel) {
    int i = blockIdx.x * 256 + threadIdx.x;
    if (i >= NN) return;
    int4 b = node_states[i];
    int st = 2 * (b.x + 2*b.y + 4*b.z + 8*b.w);
    ns[i] = st;
    int key = (st >> 1) * NGRAPH + batch_vec[i];
    unsigned long long pk = ((unsigned long long)sortable_f32(scalars[i]) << 32) | (unsigned)i;
    atomicMin(&nodeSel[key], pk);
}

__global__ void k_node2(const int* __restrict__ ns, const int* __restrict__ batch_vec,
                        const unsigned long long* __restrict__ nodeSel, int* __restrict__ row) {
    int i = blockIdx.x * 256 + threadIdx.x;
    if (i >= NN) return;
    int st = ns[i];
    int key = (st >> 1) * NGRAPH + batch_vec[i];
    unsigned win = (unsigned)(nodeSel[key] & 0xffffffffull);
    row[i] = st + (win == (unsigned)i ? 1 : 0);
}

// per-edge: static idx + edge-state idx, edge selection atomicMin, receiver histogram+rank
__global__ void k_edge1(const int4* __restrict__ edge_states, const float* __restrict__ scalars,
                        const int* __restrict__ ei0, const int* __restrict__ ei1,
                        const int* __restrict__ ns, unsigned char* __restrict__ esi,
                        unsigned long long* __restrict__ edgeSel,
                        unsigned* __restrict__ cnt, unsigned* __restrict__ rank) {
    int e = blockIdx.x * 256 + threadIdx.x;
    if (e >= NE) return;
    int4 b = edge_states[e];
    int es = b.x + 2*b.y + 4*b.z + 8*b.w;
    float sc = scalars[e];
    int s0 = ei0[e], s1 = ei1[e];
    float send = scalars[s0], recv = scalars[s1];
    int si = (sc < recv ? 1 : 0) + (send + sc < recv ? 2 : 0);
    esi[e] = (unsigned char)(es | (si << 4));
    int st = ns[s0];
    unsigned long long pk = ((unsigned long long)sortable_f32(sc) << 32) | (unsigned)e;
    atomicMin(&edgeSel[(size_t)(st >> 1) * NN + s1], pk);
    rank[e] = atomicAdd(&cnt[s1], 1u);
}

// single-block exclusive scan of cnt[NN] -> base[NN+1]
__global__ __launch_bounds__(1024) void k_scan(const unsigned* __restrict__ cnt,
                                               unsigned* __restrict__ base) {
    __shared__ unsigned part[1024];
    int t = threadIdx.x;
    int st = t * 30;
    unsigned s = 0;
    for (int k = 0; k < 30; ++k) {
        int idx = st + k;
        if (idx < NN) s += cnt[idx];
    }
    part[t] = s;
    __syncthreads();
    for (int o = 1; o < 1024; o <<= 1) {
        unsigned v = (t >= o) ? part[t - o] : 0u;
        __syncthreads();
        part[t] += v;
        __syncthreads();
    }
    unsigned run = (t == 0) ? 0u : part[t - 1];
    for (int k = 0; k < 30; ++k) {
        int idx = st + k;
        if (idx < NN) { base[idx] = run; run += cnt[idx]; }
    }
    if (t == 1023) base[NN] = part[1023];
}

// per-edge: alpha from A/B tables, scatter (key,alpha) to sorted slot — no atomics
__global__ __launch_bounds__(256) void k_edge2(const int* __restrict__ ei0,
        const int* __restrict__ ei1, const int* __restrict__ ns, const int* __restrict__ row,
        const unsigned long long* __restrict__ edgeSel, const unsigned char* __restrict__ esi,
        const int* __restrict__ rev_idx, const float* __restrict__ tabs,
        const unsigned* __restrict__ base, const unsigned* __restrict__ rank,
        uint2* __restrict__ sKey, float* __restrict__ sAlpha) {
    __shared__ float AB[2048];
    for (int j = threadIdx.x; j < 2048; j += 256) AB[j] = tabs[T_A + j];
    __syncthreads();
    int e = blockIdx.x * 256 + threadIdx.x;
    if (e >= NE) return;
    int s0 = ei0[e], s1 = ei1[e];
    int st = ns[s0];
    unsigned win = (unsigned)(edgeSel[(size_t)(st >> 1) * NN + s1] & 0xffffffffull);
    int ekrow = st + (win == (unsigned)e ? 1 : 0);
    int r0 = row[s0], r1 = row[s1];
    float alpha = AB[r1 * 32 + r0] + AB[1024 + r1 * 32 + ekrow];
    unsigned inf = esi[e];
    unsigned infr = esi[rev_idx[e]];
    unsigned pos = base[s1] + rank[e];
    sKey[pos] = make_uint2((unsigned)e | ((unsigned)r0 << 19) | ((inf & 15u) << 24)
                           | ((infr & 15u) << 28), inf >> 4);
    sAlpha[pos] = alpha;
}

// one wave per node: softmax over its segment + messages; writes edge_out + node_out.
// Zero atomics.
__global__ __launch_bounds__(256) void k_agg(
        const unsigned* __restrict__ base, const uint2* __restrict__ sKey,
        const float* __restrict__ sAlpha, const int* __restrict__ rowArr,
        const float* __restrict__ tabs, const float* __restrict__ emb_edge,
        const float* __restrict__ emb_sbv, const int* __restrict__ step_ptr,
        float* __restrict__ out_node, float* __restrict__ out_edge) {
    __shared__ float lds[5376];
    int tid = threadIdx.x;
    for (int j = tid; j < 4352; j += 256) lds[j] = tabs[j];       // TV,TC1,TC2,TC3
    for (int j = tid; j < 1024; j += 256) lds[4352 + j] = emb_edge[j];
    __syncthreads();
    int step = step_ptr[0];
    float invTau;
    if (step == -1) invTau = 1.0f;
    else { float frac = fminf((float)step / 10000.f, 1.f); invTau = 1.0f / (3.0f + (0.1f - 3.0f) * frac); }
    int lane = tid & 63;
    int i = blockIdx.x * 4 + (tid >> 6);
    if (i >= NN) return;
    unsigned j0 = base[i], j1 = base[i + 1];
    // pass 1: segment max (lane-parallel)
    float m = -3.4e38f;
    for (unsigned j = j0 + lane; j < j1; j += 64) m = fmaxf(m, sAlpha[j]);
    #pragma unroll
    for (int o = 1; o < 64; o <<= 1) m = fmaxf(m, __shfl_xor(m, o));
    // pass 2: segment sum of exp
    float s = 0.f;
    for (unsigned j = j0 + lane; j < j1; j += 64) s += __expf((sAlpha[j] - m) * invTau);
    #pragma unroll
    for (int o = 1; o < 64; o <<= 1) s += __shfl_xor(s, o);
    float invS = 1.f / s;
    // pass 3: per-edge message, edge_out write, register node accumulate
    float acc = 0.f;
    for (unsigned j = j0; j < j1; ++j) {
        uint2 k = sKey[j];
        float a = sAlpha[j];
        float p = __expf((a - m) * invTau) * invS;
        unsigned e = k.x & 0x7ffffu;
        int r0 = (k.x >> 19) & 31, es = (k.x >> 24) & 15, esr = (k.x >> 28) & 15, si = k.y & 3;
        float msg = p * (lds[(r0 << 6) + lane] + lds[2048 + (es << 6) + lane]
                       + lds[3072 + (esr << 6) + lane] + lds[4096 + (si << 6) + lane]);
        out_edge[(size_t)e * 64 + lane] = lds[4352 + (es << 6) + lane] + msg;
        acc += msg;
    }
    out_node[(size_t)i * 64 + lane] = emb_sbv[(rowArr[i] << 6) + lane] + acc;
}

extern "C" void kernel_launch(void* const* d_in, const int* in_sizes, int n_in,
                              void* d_out, int out_size, void* d_ws, size_t ws_size,
                              hipStream_t stream) {
    const int4*  node_states = (const int4*)d_in[0];
    const int4*  edge_states = (const int4*)d_in[1];
    const float* scalars     = (const float*)d_in[2];
    const int*   edge_index  = (const int*)d_in[3];
    const int*   batch_vec   = (const int*)d_in[4];
    const int*   rev_idx     = (const int*)d_in[5];
    const float* emb_edge    = (const float*)d_in[6];
    const float* emb_sbv     = (const float*)d_in[7];
    const float* emb_sbr     = (const float*)d_in[8];
    const float* emb_static  = (const float*)d_in[9];
    const float* Wq  = (const float*)d_in[10];
    const float* Wk  = (const float*)d_in[11];
    const float* Wv  = (const float*)d_in[12];
    const float* Wek = (const float*)d_in[13];
    const float* Wc  = (const float*)d_in[15];
    const int*   step = (const int*)d_in[16];

    const int* ei0 = edge_index;
    const int* ei1 = edge_index + NE;

    char* ws = (char*)d_ws;
    // workspace layout (byte offsets):
    // [0,         3,840,000)  edgeSel u64 16*NN
    // [3,840,000, 3,848,192)  nodeSel u64 1024
    // [3,848,192, 3,968,192)  ns i32 NN
    // [3,968,192, 4,088,192)  rowArr i32 NN
    // [4,088,192, 4,478,192)  esi u8 NE
    // [4,478,192, 6,038,192)  rank u32 NE
    // [6,038,192, 6,158,256)  cnt u32 NN (pad)
    // [6,158,256, 6,278,320)  base u32 NN+1 (pad)
    // [6,278,320, 9,398,320)  sKey uint2 NE
    // [9,398,320, 10,958,320) sAlpha f32 NE
    // [10,958,320, 11,008,496) tabs f32 12544
    unsigned long long* edgeSel = (unsigned long long*)(ws);
    unsigned long long* nodeSel = (unsigned long long*)(ws + 3840000);
    int*      ns     = (int*)(ws + 3848192);
    int*      rowArr = (int*)(ws + 3968192);
    unsigned char* esi = (unsigned char*)(ws + 4088192);
    unsigned* rank   = (unsigned*)(ws + 4478192);
    unsigned* cnt    = (unsigned*)(ws + 6038192);
    unsigned* baseA  = (unsigned*)(ws + 6158256);
    uint2*    sKey   = (uint2*)(ws + 6278320);
    float*    sAlpha = (float*)(ws + 9398320);
    float*    tabs   = (float*)(ws + 10958320);

    float* out_node = (float*)d_out;
    float* out_edge = out_node + (size_t)NN * HH;

    // init: selection slots to 0xFF (max), histogram to 0
    hipMemsetAsync(ws, 0xFF, 3848192, stream);
    hipMemsetAsync(ws + 6038192, 0, 120000, stream);

    hipLaunchKernelGGL(k_tab1, dim3(41), dim3(256), 0, stream,
                       emb_sbv, emb_sbr, emb_edge, emb_static, Wq, Wk, Wv, Wek, Wc, tabs);
    hipLaunchKernelGGL(k_tab2, dim3(8), dim3(256), 0, stream, tabs);

    int nb_node = (NN + 255) / 256;
    int nb_edge = (NE + 255) / 256;

    hipLaunchKernelGGL(k_node1, dim3(nb_node), dim3(256), 0, stream,
                       node_states, scalars, batch_vec, ns, nodeSel);
    hipLaunchKernelGGL(k_edge1, dim3(nb_edge), dim3(256), 0, stream,
                       edge_states, scalars, ei0, ei1, ns, esi, edgeSel, cnt, rank);
    hipLaunchKernelGGL(k_node2, dim3(nb_node), dim3(256), 0, stream,
                       ns, batch_vec, nodeSel, rowArr);
    hipLaunchKernelGGL(k_scan, dim3(1), dim3(1024), 0, stream, cnt, baseA);
    hipLaunchKernelGGL(k_edge2, dim3(nb_edge), dim3(256), 0, stream,
                       ei0, ei1, ns, rowArr, edgeSel, esi, rev_idx, tabs, baseA, rank,
                       sKey, sAlpha);
    hipLaunchKernelGGL(k_agg, dim3(NN / 4), dim3(256), 0, stream,
                       baseA, sKey, sAlpha, rowArr, tabs, emb_edge, emb_sbv, step,
                       out_node, out_edge);
}

// Round 5
// 171.946 us; speedup vs baseline: 1.3072x; 1.0422x over previous
//
#include <hip/hip_runtime.h>

#define NN 30000
#define NE 390000
#define HH 64
#define NGRAPH 64
#define AGG_BLOCKS 1024

// ---------- sortable float encoding (ascending order preserved in uint) ----------
__device__ __forceinline__ unsigned sortable_f32(float f) {
    unsigned u = __float_as_uint(f);
    return (u & 0x80000000u) ? ~u : (u | 0x80000000u);
}

// tabs layout (float offsets):
// TV=0 (32x64), TC1=2048 (16x64), TC2=3072 (16x64), TC3=4096 (4x64),
// A=4352 (32x32), B=5376 (32x32), scratch: TQ=6400, TK=8448, TEK=10496
#define T_V   0
#define T_C1  2048
#define T_C2  3072
#define T_C3  4096
#define T_A   4352
#define T_B   5376
#define T_Q   6400
#define T_K   8448
#define T_EK  10496

__global__ void k_tab1(const float* __restrict__ emb_sbv, const float* __restrict__ emb_sbr,
                       const float* __restrict__ emb_edge, const float* __restrict__ emb_static,
                       const float* __restrict__ Wq, const float* __restrict__ Wk,
                       const float* __restrict__ Wv, const float* __restrict__ Wek,
                       const float* __restrict__ Wc, float* __restrict__ tabs) {
    int idx = blockIdx.x * 256 + threadIdx.x;
    if (idx >= 10496) return;
    float acc = 0.f;
    if (idx < 2048) {              // TV = emb_sbv @ Wv.T
        int r = idx >> 6, h = idx & 63;
        for (int j = 0; j < 64; ++j) acc += emb_sbv[r*64+j] * Wv[h*64+j];
        tabs[T_V + idx] = acc;
    } else if (idx < 3072) {       // TC1 = emb_edge @ Wc[:,0:64].T
        int t = idx - 2048; int r = t >> 6, h = t & 63;
        for (int j = 0; j < 64; ++j) acc += emb_edge[r*64+j] * Wc[h*192+j];
        tabs[T_C1 + t] = acc;
    } else if (idx < 4096) {       // TC2 = emb_edge @ Wc[:,64:128].T
        int t = idx - 3072; int r = t >> 6, h = t & 63;
        for (int j = 0; j < 64; ++j) acc += emb_edge[r*64+j] * Wc[h*192+64+j];
        tabs[T_C2 + t] = acc;
    } else if (idx < 4352) {       // TC3 = emb_static @ Wc[:,128:192].T
        int t = idx - 4096; int r = t >> 6, h = t & 63;
        for (int j = 0; j < 64; ++j) acc += emb_static[r*64+j] * Wc[h*192+128+j];
        tabs[T_C3 + t] = acc;
    } else if (idx < 6400) {       // TQ (scratch)
        int t = idx - 4352; int r = t >> 6, h = t & 63;
        for (int j = 0; j < 64; ++j) acc += emb_sbv[r*64+j] * Wq[h*64+j];
        tabs[T_Q + t] = acc;
    } else if (idx < 8448) {       // TK (scratch)
        int t = idx - 6400; int r = t >> 6, h = t & 63;
        for (int j = 0; j < 64; ++j) acc += emb_sbv[r*64+j] * Wk[h*64+j];
        tabs[T_K + t] = acc;
    } else {                       // TEK (scratch)
        int t = idx - 8448; int r = t >> 6, h = t & 63;
        for (int j = 0; j < 64; ++j) acc += emb_sbr[r*64+j] * Wek[h*64+j];
        tabs[T_EK + t] = acc;
    }
}

__global__ void k_tab2(float* __restrict__ tabs) {
    int idx = blockIdx.x * 256 + threadIdx.x;
    if (idx >= 2048) return;
    const float* TQ = tabs + T_Q;
    float acc = 0.f;
    if (idx < 1024) {              // A[r1][r0] = TQ[r1]·TK[r0] / 8
        int r1 = idx >> 5, r0 = idx & 31;
        const float* TK = tabs + T_K;
        for (int j = 0; j < 64; ++j) acc += TQ[r1*64+j] * TK[r0*64+j];
        tabs[T_A + idx] = acc * 0.125f;
    } else {                       // B[r1][rk] = TQ[r1]·TEK[rk] / 8
        int t = idx - 1024; int r1 = t >> 5, rk = t & 31;
        const float* TEK = tabs + T_EK;
        for (int j = 0; j < 64; ++j) acc += TQ[r1*64+j] * TEK[rk*64+j];
        tabs[T_B + t] = acc * 0.125f;
    }
}

// per-node even state + node selection atomicMin (1024 keys, L2-resident)
__global__ void k_node1(const int4* __restrict__ node_states, const float* __restrict__ scalars,
                        const int* __restrict__ batch_vec, int* __restrict__ ns,
                        unsigned long long* __restrict__ nodeSel) {
    int i = blockIdx.x * 256 + threadIdx.x;
    if (i >= NN) return;
    int4 b = node_states[i];
    int st = 2 * (b.x + 2*b.y + 4*b.z + 8*b.w);
    ns[i] = st;
    int key = (st >> 1) * NGRAPH + batch_vec[i];
    unsigned long long pk = ((unsigned long long)sortable_f32(scalars[i]) << 32) | (unsigned)i;
    atomicMin(&nodeSel[key], pk);
}

// per-edge: esi (edge-state | static-idx), receiver rank (ONLY per-edge atomic)
__global__ void k_edge1(const int4* __restrict__ edge_states, const float* __restrict__ scalars,
                        const int* __restrict__ ei0, const int* __restrict__ ei1,
                        unsigned char* __restrict__ esi,
                        unsigned* __restrict__ cnt, unsigned* __restrict__ rank) {
    int e = blockIdx.x * 256 + threadIdx.x;
    if (e >= NE) return;
    int4 b = edge_states[e];
    int es = b.x + 2*b.y + 4*b.z + 8*b.w;
    float sc = scalars[e];
    int s0 = ei0[e], s1 = ei1[e];
    float send = scalars[s0], recv = scalars[s1];
    int si = (sc < recv ? 1 : 0) + (send + sc < recv ? 2 : 0);
    esi[e] = (unsigned char)(es | (si << 4));
    rank[e] = atomicAdd(&cnt[s1], 1u);
}

// single-block: exclusive scan cnt->base, plus node row resolve (folded node2)
__global__ __launch_bounds__(1024) void k_scan(const unsigned* __restrict__ cnt,
        unsigned* __restrict__ base, const int* __restrict__ ns,
        const int* __restrict__ batch_vec, const unsigned long long* __restrict__ nodeSel,
        int* __restrict__ rowArr) {
    __shared__ unsigned part[1024];
    int t = threadIdx.x;
    int st0 = t * 30;
    unsigned local[30];
    unsigned s = 0;
    #pragma unroll
    for (int k = 0; k < 30; ++k) {
        int idx = st0 + k;
        local[k] = (idx < NN) ? cnt[idx] : 0u;
        s += local[k];
    }
    part[t] = s;
    __syncthreads();
    for (int o = 1; o < 1024; o <<= 1) {
        unsigned v = (t >= o) ? part[t - o] : 0u;
        __syncthreads();
        part[t] += v;
        __syncthreads();
    }
    unsigned run = (t == 0) ? 0u : part[t - 1];
    #pragma unroll
    for (int k = 0; k < 30; ++k) {
        int idx = st0 + k;
        if (idx < NN) { base[idx] = run; run += local[k]; }
    }
    if (t == 1023) base[NN] = part[1023];
    #pragma unroll
    for (int k = 0; k < 30; ++k) {
        int idx = st0 + k;
        if (idx < NN) {
            int st = ns[idx];
            int key = (st >> 1) * NGRAPH + batch_vec[idx];
            unsigned win = (unsigned)(nodeSel[key] & 0xffffffffull);
            rowArr[idx] = st + (win == (unsigned)idx ? 1 : 0);
        }
    }
}

// per-edge: pack payload, scatter to CSR slot — no atomics
__global__ __launch_bounds__(256) void k_edge2(const int* __restrict__ ei0,
        const int* __restrict__ ei1, const int* __restrict__ rowArr,
        const unsigned char* __restrict__ esi, const int* __restrict__ rev_idx,
        const float* __restrict__ scalars, const unsigned* __restrict__ base,
        const unsigned* __restrict__ rank, uint2* __restrict__ sKey,
        float* __restrict__ sScal) {
    int e = blockIdx.x * 256 + threadIdx.x;
    if (e >= NE) return;
    int s0 = ei0[e], s1 = ei1[e];
    unsigned r0w = (unsigned)rowArr[s0];          // row of sender = st or st+1
    unsigned stq = (r0w & ~1u) >> 1;              // st>>1, 4 bits
    unsigned inf = esi[e];
    unsigned infr = esi[rev_idx[e]];
    unsigned pos = base[s1] + rank[e];
    sKey[pos] = make_uint2((unsigned)e | (r0w << 19) | ((inf & 15u) << 24) | ((infr & 15u) << 28),
                           stq | ((inf >> 4) << 4));
    sScal[pos] = scalars[e];
}

// one wave per node: in-wave argmin (edge_K select), softmax (no max-shift),
// quad-parallel messages. Writes edge_out + node_out. Zero atomics.
__global__ __launch_bounds__(256) void k_agg(
        const unsigned* __restrict__ base, const uint2* __restrict__ sKey,
        const float* __restrict__ sScal, const int* __restrict__ rowArr,
        const float* __restrict__ tabs, const float* __restrict__ emb_edge,
        const float* __restrict__ emb_sbv, const int* __restrict__ step_ptr,
        float* __restrict__ out_node, float* __restrict__ out_edge) {
    // LDS: [0,6400) tabs (TV,TC1,TC2,TC3,A,B); [6400,7424) emb_edge; [7424,9472) emb_sbv
    __shared__ float lds[9472];
    __shared__ unsigned scr[4][32];   // per-wave argmin scratch: [16] min-sc, [16] min-e
    int tid = threadIdx.x;
    for (int j = tid; j < 6400; j += 256) lds[j] = tabs[j];
    for (int j = tid; j < 1024; j += 256) lds[6400 + j] = emb_edge[j];
    for (int j = tid; j < 2048; j += 256) lds[7424 + j] = emb_sbv[j];
    __syncthreads();
    int step = step_ptr[0];
    float invTau;
    if (step == -1) invTau = 1.0f;
    else { float frac = fminf((float)step / 10000.f, 1.f); invTau = 1.0f / (3.0f + (0.1f - 3.0f) * frac); }
    int wid = tid >> 6, lane = tid & 63;
    unsigned* mySc = scr[wid];
    unsigned* myE  = scr[wid] + 16;
    int q = lane >> 4, cidx = (lane & 15) << 2;
    for (int i = blockIdx.x * 4 + wid; i < NN; i += AGG_BLOCKS * 4) {
        unsigned j0 = base[i], j1 = base[i + 1];
        int d = (int)(j1 - j0);
        int r1 = rowArr[i];
        const float* Arow = lds + T_A + r1 * 32;
        const float* Brow = lds + T_B + r1 * 32;
        float4 acc = {0.f, 0.f, 0.f, 0.f};
        if (lane < 16) { mySc[lane] = 0xffffffffu; myE[lane] = 0xffffffffu; }
        __builtin_amdgcn_sched_barrier(0);
        if (d > 0 && d <= 64) {
            // ---- register fast path ----
            bool act = lane < d;
            uint2 key = act ? sKey[j0 + lane] : make_uint2(0u, 0u);
            float sc  = act ? sScal[j0 + lane] : 0.f;
            unsigned scs = sortable_f32(sc);
            unsigned g = key.y & 15u;
            unsigned e19 = key.x & 0x7ffffu;
            if (act) atomicMin(&mySc[g], scs);
            __builtin_amdgcn_sched_barrier(0);
            unsigned ms = mySc[g];
            if (act && scs == ms) atomicMin(&myE[g], e19);
            __builtin_amdgcn_sched_barrier(0);
            bool win = act && (myE[g] == e19);
            int r0 = (key.x >> 19) & 31;
            int ekrow = ((int)(key.y & 15u) << 1) + (win ? 1 : 0);
            float ex = act ? __expf((Arow[r0] + Brow[ekrow]) * invTau) : 0.f;
            float s = ex;
            #pragma unroll
            for (int o = 1; o < 64; o <<= 1) s += __shfl_xor(s, o);
            float p = ex / s;
            int nIt = (d + 3) >> 2;
            for (int it = 0; it < nIt; ++it) {
                int jj = it * 4 + q;
                unsigned kx = __shfl(key.x, jj);
                unsigned ky = (unsigned)__shfl((int)key.y, jj);
                float pp = __shfl(p, jj);
                if (jj < d) {
                    unsigned e = kx & 0x7ffffu;
                    int rr0 = (kx >> 19) & 31, es = (kx >> 24) & 15, esr = (kx >> 28) & 15;
                    int si = (ky >> 4) & 3;
                    float4 tv = *(const float4*)&lds[(rr0 << 6) + cidx];
                    float4 c1 = *(const float4*)&lds[T_C1 + (es << 6) + cidx];
                    float4 c2 = *(const float4*)&lds[T_C2 + (esr << 6) + cidx];
                    float4 c3 = *(const float4*)&lds[T_C3 + (si << 6) + cidx];
                    float4 ee = *(const float4*)&lds[6400 + (es << 6) + cidx];
                    float4 o;
                    o.x = pp * (tv.x + c1.x + c2.x + c3.x);
                    o.y = pp * (tv.y + c1.y + c2.y + c3.y);
                    o.z = pp * (tv.z + c1.z + c2.z + c3.z);
                    o.w = pp * (tv.w + c1.w + c2.w + c3.w);
                    acc.x += o.x; acc.y += o.y; acc.z += o.z; acc.w += o.w;
                    o.x += ee.x; o.y += ee.y; o.z += ee.z; o.w += ee.w;
                    *(float4*)&out_edge[(size_t)e * 64 + cidx] = o;
                }
            }
        } else if (d > 64) {
            // ---- chunked general path ----
            for (unsigned c = j0; c < j1; c += 64) {
                unsigned j = c + lane;
                if (j < j1) {
                    uint2 key = sKey[j];
                    atomicMin(&mySc[key.y & 15u], sortable_f32(sScal[j]));
                }
            }
            __builtin_amdgcn_sched_barrier(0);
            for (unsigned c = j0; c < j1; c += 64) {
                unsigned j = c + lane;
                if (j < j1) {
                    uint2 key = sKey[j];
                    unsigned g = key.y & 15u;
                    if (sortable_f32(sScal[j]) == mySc[g]) atomicMin(&myE[g], key.x & 0x7ffffu);
                }
            }
            __builtin_amdgcn_sched_barrier(0);
            float s = 0.f;
            for (unsigned c = j0; c < j1; c += 64) {
                unsigned j = c + lane;
                if (j < j1) {
                    uint2 key = sKey[j];
                    bool win = (myE[key.y & 15u] == (key.x & 0x7ffffu));
                    int r0 = (key.x >> 19) & 31;
                    int ekrow = ((int)(key.y & 15u) << 1) + (win ? 1 : 0);
                    s += __expf((Arow[r0] + Brow[ekrow]) * invTau);
                }
            }
            #pragma unroll
            for (int o = 1; o < 64; o <<= 1) s += __shfl_xor(s, o);
            float invS = 1.f / s;
            for (unsigned c = j0; c < j1; c += 4) {
                unsigned j = c + q;
                if (j < j1) {
                    uint2 key = sKey[j];
                    bool win = (myE[key.y & 15u] == (key.x & 0x7ffffu));
                    int r0 = (key.x >> 19) & 31;
                    int ekrow = ((int)(key.y & 15u) << 1) + (win ? 1 : 0);
                    float pp = __expf((Arow[r0] + Brow[ekrow]) * invTau) * invS;
                    unsigned e = key.x & 0x7ffffu;
                    int es = (key.x >> 24) & 15, esr = (key.x >> 28) & 15, si = (key.y >> 4) & 3;
                    float4 tv = *(const float4*)&lds[(r0 << 6) + cidx];
                    float4 c1 = *(const float4*)&lds[T_C1 + (es << 6) + cidx];
                    float4 c2 = *(const float4*)&lds[T_C2 + (esr << 6) + cidx];
                    float4 c3 = *(const float4*)&lds[T_C3 + (si << 6) + cidx];
                    float4 ee = *(const float4*)&lds[6400 + (es << 6) + cidx];
                    float4 o;
                    o.x = pp * (tv.x + c1.x + c2.x + c3.x);
                    o.y = pp * (tv.y + c1.y + c2.y + c3.y);
                    o.z = pp * (tv.z + c1.z + c2.z + c3.z);
                    o.w = pp * (tv.w + c1.w + c2.w + c3.w);
                    acc.x += o.x; acc.y += o.y; acc.z += o.z; acc.w += o.w;
                    o.x += ee.x; o.y += ee.y; o.z += ee.z; o.w += ee.w;
                    *(float4*)&out_edge[(size_t)e * 64 + cidx] = o;
                }
            }
        }
        // node reduce across quad groups and write
        acc.x += __shfl_xor(acc.x, 16); acc.y += __shfl_xor(acc.y, 16);
        acc.z += __shfl_xor(acc.z, 16); acc.w += __shfl_xor(acc.w, 16);
        acc.x += __shfl_xor(acc.x, 32); acc.y += __shfl_xor(acc.y, 32);
        acc.z += __shfl_xor(acc.z, 32); acc.w += __shfl_xor(acc.w, 32);
        if (lane < 16) {
            float4 nb = *(const float4*)&lds[7424 + (r1 << 6) + cidx];
            float4 o;
            o.x = nb.x + acc.x; o.y = nb.y + acc.y; o.z = nb.z + acc.z; o.w = nb.w + acc.w;
            *(float4*)&out_node[(size_t)i * 64 + cidx] = o;
        }
    }
}

extern "C" void kernel_launch(void* const* d_in, const int* in_sizes, int n_in,
                              void* d_out, int out_size, void* d_ws, size_t ws_size,
                              hipStream_t stream) {
    const int4*  node_states = (const int4*)d_in[0];
    const int4*  edge_states = (const int4*)d_in[1];
    const float* scalars     = (const float*)d_in[2];
    const int*   edge_index  = (const int*)d_in[3];
    const int*   batch_vec   = (const int*)d_in[4];
    const int*   rev_idx     = (const int*)d_in[5];
    const float* emb_edge    = (const float*)d_in[6];
    const float* emb_sbv     = (const float*)d_in[7];
    const float* emb_sbr     = (const float*)d_in[8];
    const float* emb_static  = (const float*)d_in[9];
    const float* Wq  = (const float*)d_in[10];
    const float* Wk  = (const float*)d_in[11];
    const float* Wv  = (const float*)d_in[12];
    const float* Wek = (const float*)d_in[13];
    const float* Wc  = (const float*)d_in[15];
    const int*   step = (const int*)d_in[16];

    const int* ei0 = edge_index;
    const int* ei1 = edge_index + NE;

    char* ws = (char*)d_ws;
    // workspace layout (byte offsets, NON-OVERLAPPING, 64-ish aligned):
    // [0,        120000)   ns i32 NN
    // [120000,   240000)   rowArr i32 NN
    // [240000,   630000)   esi u8 NE
    // [630000,  2190000)   rank u32 NE
    // [2190000, 2310000)   cnt u32 NN
    // [2310080, 2430084)   base u32 NN+1          (ends 2430084)
    // [2430144, 5550144)   sKey uint2 NE          (starts AFTER base end — R4 bug fixed)
    // [5550144, 7110144)   sScal f32 NE
    // [7110144, 7118336)   nodeSel u64 1024
    // [7118336, 7168512)   tabs f32 12544
    int*      ns     = (int*)(ws);
    int*      rowArr = (int*)(ws + 120000);
    unsigned char* esi = (unsigned char*)(ws + 240000);
    unsigned* rank   = (unsigned*)(ws + 630000);
    unsigned* cnt    = (unsigned*)(ws + 2190000);
    unsigned* baseA  = (unsigned*)(ws + 2310080);
    uint2*    sKey   = (uint2*)(ws + 2430144);
    float*    sScal  = (float*)(ws + 5550144);
    unsigned long long* nodeSel = (unsigned long long*)(ws + 7110144);
    float*    tabs   = (float*)(ws + 7118336);

    float* out_node = (float*)d_out;
    float* out_edge = out_node + (size_t)NN * HH;

    hipMemsetAsync(cnt, 0, NN * 4, stream);
    hipMemsetAsync(nodeSel, 0xFF, 1024 * 8, stream);

    hipLaunchKernelGGL(k_tab1, dim3(41), dim3(256), 0, stream,
                       emb_sbv, emb_sbr, emb_edge, emb_static, Wq, Wk, Wv, Wek, Wc, tabs);
    hipLaunchKernelGGL(k_tab2, dim3(8), dim3(256), 0, stream, tabs);

    int nb_node = (NN + 255) / 256;
    int nb_edge = (NE + 255) / 256;

    hipLaunchKernelGGL(k_node1, dim3(nb_node), dim3(256), 0, stream,
                       node_states, scalars, batch_vec, ns, nodeSel);
    hipLaunchKernelGGL(k_edge1, dim3(nb_edge), dim3(256), 0, stream,
                       edge_states, scalars, ei0, ei1, esi, cnt, rank);
    hipLaunchKernelGGL(k_scan, dim3(1), dim3(1024), 0, stream,
                       cnt, baseA, ns, batch_vec, nodeSel, rowArr);
    hipLaunchKernelGGL(k_edge2, dim3(nb_edge), dim3(256), 0, stream,
                       ei0, ei1, rowArr, esi, rev_idx, scalars, baseA, rank, sKey, sScal);
    hipLaunchKernelGGL(k_agg, dim3(AGG_BLOCKS), dim3(256), 0, stream,
                       baseA, sKey, sScal, rowArr, tabs, emb_edge, emb_sbv, step,
                       out_node, out_edge);
}

// Round 6
// 92.829 us; speedup vs baseline: 2.4213x; 1.8523x over previous
//
#include <hip/hip_runtime.h>

#define NN 30000
#define NE 390000
#define HH 64
#define NGRAPH 64
#define AGG_BLOCKS 1024
#define NB 118   // ceil(NN/256)

// ---------- sortable float encoding (ascending order preserved in uint) ----------
__device__ __forceinline__ unsigned sortable_f32(float f) {
    unsigned u = __float_as_uint(f);
    return (u & 0x80000000u) ? ~u : (u | 0x80000000u);
}

// tabs layout (float offsets):
// TV=0 (32x64), TC1=2048 (16x64), TC2=3072 (16x64), TC3=4096 (4x64),
// A=4352 (32x32), B=5376 (32x32), scratch: TQ=6400, TK=8448, TEK=10496
#define T_V   0
#define T_C1  2048
#define T_C2  3072
#define T_C3  4096
#define T_A   4352
#define T_B   5376
#define T_Q   6400
#define T_K   8448
#define T_EK  10496

__global__ void k_tab1(const float* __restrict__ emb_sbv, const float* __restrict__ emb_sbr,
                       const float* __restrict__ emb_edge, const float* __restrict__ emb_static,
                       const float* __restrict__ Wq, const float* __restrict__ Wk,
                       const float* __restrict__ Wv, const float* __restrict__ Wek,
                       const float* __restrict__ Wc, float* __restrict__ tabs) {
    int idx = blockIdx.x * 256 + threadIdx.x;
    if (idx >= 10496) return;
    float acc = 0.f;
    if (idx < 2048) {              // TV = emb_sbv @ Wv.T
        int r = idx >> 6, h = idx & 63;
        for (int j = 0; j < 64; ++j) acc += emb_sbv[r*64+j] * Wv[h*64+j];
        tabs[T_V + idx] = acc;
    } else if (idx < 3072) {       // TC1 = emb_edge @ Wc[:,0:64].T
        int t = idx - 2048; int r = t >> 6, h = t & 63;
        for (int j = 0; j < 64; ++j) acc += emb_edge[r*64+j] * Wc[h*192+j];
        tabs[T_C1 + t] = acc;
    } else if (idx < 4096) {       // TC2 = emb_edge @ Wc[:,64:128].T
        int t = idx - 3072; int r = t >> 6, h = t & 63;
        for (int j = 0; j < 64; ++j) acc += emb_edge[r*64+j] * Wc[h*192+64+j];
        tabs[T_C2 + t] = acc;
    } else if (idx < 4352) {       // TC3 = emb_static @ Wc[:,128:192].T
        int t = idx - 4096; int r = t >> 6, h = t & 63;
        for (int j = 0; j < 64; ++j) acc += emb_static[r*64+j] * Wc[h*192+128+j];
        tabs[T_C3 + t] = acc;
    } else if (idx < 6400) {       // TQ (scratch)
        int t = idx - 4352; int r = t >> 6, h = t & 63;
        for (int j = 0; j < 64; ++j) acc += emb_sbv[r*64+j] * Wq[h*64+j];
        tabs[T_Q + t] = acc;
    } else if (idx < 8448) {       // TK (scratch)
        int t = idx - 6400; int r = t >> 6, h = t & 63;
        for (int j = 0; j < 64; ++j) acc += emb_sbv[r*64+j] * Wk[h*64+j];
        tabs[T_K + t] = acc;
    } else {                       // TEK (scratch)
        int t = idx - 8448; int r = t >> 6, h = t & 63;
        for (int j = 0; j < 64; ++j) acc += emb_sbr[r*64+j] * Wek[h*64+j];
        tabs[T_EK + t] = acc;
    }
}

__global__ void k_tab2(float* __restrict__ tabs) {
    int idx = blockIdx.x * 256 + threadIdx.x;
    if (idx >= 2048) return;
    const float* TQ = tabs + T_Q;
    float acc = 0.f;
    if (idx < 1024) {              // A[r1][r0] = TQ[r1]·TK[r0] / 8
        int r1 = idx >> 5, r0 = idx & 31;
        const float* TK = tabs + T_K;
        for (int j = 0; j < 64; ++j) acc += TQ[r1*64+j] * TK[r0*64+j];
        tabs[T_A + idx] = acc * 0.125f;
    } else {                       // B[r1][rk] = TQ[r1]·TEK[rk] / 8
        int t = idx - 1024; int r1 = t >> 5, rk = t & 31;
        const float* TEK = tabs + T_EK;
        for (int j = 0; j < 64; ++j) acc += TQ[r1*64+j] * TEK[rk*64+j];
        tabs[T_B + t] = acc * 0.125f;
    }
}

// per-node even state + node selection atomicMin (1024 keys, L2-resident)
__global__ void k_node1(const int4* __restrict__ node_states, const float* __restrict__ scalars,
                        const int* __restrict__ batch_vec, int* __restrict__ ns,
                        unsigned long long* __restrict__ nodeSel) {
    int i = blockIdx.x * 256 + threadIdx.x;
    if (i >= NN) return;
    int4 b = node_states[i];
    int st = 2 * (b.x + 2*b.y + 4*b.z + 8*b.w);
    ns[i] = st;
    int key = (st >> 1) * NGRAPH + batch_vec[i];
    unsigned long long pk = ((unsigned long long)sortable_f32(scalars[i]) << 32) | (unsigned)i;
    atomicMin(&nodeSel[key], pk);
}

// per-edge: esi (edge-state | static-idx), receiver rank (ONLY per-edge atomic)
__global__ void k_edge1(const int4* __restrict__ edge_states, const float* __restrict__ scalars,
                        const int* __restrict__ ei0, const int* __restrict__ ei1,
                        unsigned char* __restrict__ esi,
                        unsigned* __restrict__ cnt, unsigned* __restrict__ rank) {
    int e = blockIdx.x * 256 + threadIdx.x;
    if (e >= NE) return;
    int4 b = edge_states[e];
    int es = b.x + 2*b.y + 4*b.z + 8*b.w;
    float sc = scalars[e];
    int s0 = ei0[e], s1 = ei1[e];
    float send = scalars[s0], recv = scalars[s1];
    int si = (sc < recv ? 1 : 0) + (send + sc < recv ? 2 : 0);
    esi[e] = (unsigned char)(es | (si << 4));
    rank[e] = atomicAdd(&cnt[s1], 1u);
}

// ---- device-wide scan, 3 parallel stages (replaces single-block k_scan) ----
__global__ __launch_bounds__(256) void k_bsum(const unsigned* __restrict__ cnt,
                                              unsigned* __restrict__ bsum) {
    __shared__ unsigned red[256];
    int t = threadIdx.x;
    int i = blockIdx.x * 256 + t;
    red[t] = (i < NN) ? cnt[i] : 0u;
    __syncthreads();
    for (int o = 128; o > 0; o >>= 1) {
        if (t < o) red[t] += red[t + o];
        __syncthreads();
    }
    if (t == 0) bsum[blockIdx.x] = red[0];
}

__global__ __launch_bounds__(128) void k_sscan(const unsigned* __restrict__ bsum,
                                               unsigned* __restrict__ bbase,
                                               unsigned* __restrict__ base) {
    __shared__ unsigned s[128];
    int t = threadIdx.x;
    unsigned v = (t < NB) ? bsum[t] : 0u;
    s[t] = v;
    __syncthreads();
    for (int o = 1; o < 128; o <<= 1) {
        unsigned u = (t >= o) ? s[t - o] : 0u;
        __syncthreads();
        s[t] += u;
        __syncthreads();
    }
    if (t < NB) bbase[t] = s[t] - v;          // exclusive
    if (t == 127) { bbase[NB] = s[127]; base[NN] = s[127]; }
}

__global__ __launch_bounds__(256) void k_base(const unsigned* __restrict__ cnt,
        const unsigned* __restrict__ bbase, unsigned* __restrict__ base,
        const int* __restrict__ ns, const int* __restrict__ batch_vec,
        const unsigned long long* __restrict__ nodeSel, int* __restrict__ rowArr) {
    __shared__ unsigned s[256];
    int t = threadIdx.x;
    int i = blockIdx.x * 256 + t;
    unsigned v = (i < NN) ? cnt[i] : 0u;
    s[t] = v;
    __syncthreads();
    for (int o = 1; o < 256; o <<= 1) {
        unsigned u = (t >= o) ? s[t - o] : 0u;
        __syncthreads();
        s[t] += u;
        __syncthreads();
    }
    if (i < NN) {
        base[i] = bbase[blockIdx.x] + s[t] - v;
        int st = ns[i];
        int key = (st >> 1) * NGRAPH + batch_vec[i];
        unsigned win = (unsigned)(nodeSel[key] & 0xffffffffull);
        rowArr[i] = st + (win == (unsigned)i ? 1 : 0);
    }
}

// per-edge: pack payload, scatter to CSR slot — no atomics
__global__ __launch_bounds__(256) void k_edge2(const int* __restrict__ ei0,
        const int* __restrict__ ei1, const int* __restrict__ rowArr,
        const unsigned char* __restrict__ esi, const int* __restrict__ rev_idx,
        const float* __restrict__ scalars, const unsigned* __restrict__ base,
        const unsigned* __restrict__ rank, uint2* __restrict__ sKey,
        float* __restrict__ sScal) {
    int e = blockIdx.x * 256 + threadIdx.x;
    if (e >= NE) return;
    int s0 = ei0[e], s1 = ei1[e];
    unsigned r0w = (unsigned)rowArr[s0];          // row of sender = st or st+1
    unsigned stq = (r0w & ~1u) >> 1;              // st>>1, 4 bits
    unsigned inf = esi[e];
    unsigned infr = esi[rev_idx[e]];
    unsigned pos = base[s1] + rank[e];
    sKey[pos] = make_uint2((unsigned)e | (r0w << 19) | ((inf & 15u) << 24) | ((infr & 15u) << 28),
                           stq | ((inf >> 4) << 4));
    sScal[pos] = scalars[e];
}

// one wave per node: in-wave argmin (edge_K select), softmax (no max-shift),
// quad-parallel messages. Writes edge_out + node_out. Zero atomics.
__global__ __launch_bounds__(256) void k_agg(
        const unsigned* __restrict__ base, const uint2* __restrict__ sKey,
        const float* __restrict__ sScal, const int* __restrict__ rowArr,
        const float* __restrict__ tabs, const float* __restrict__ emb_edge,
        const float* __restrict__ emb_sbv, const int* __restrict__ step_ptr,
        float* __restrict__ out_node, float* __restrict__ out_edge) {
    // LDS: [0,6400) tabs (TV,TC1,TC2,TC3,A,B); [6400,7424) emb_edge; [7424,9472) emb_sbv
    __shared__ float lds[9472];
    __shared__ unsigned scr[4][32];   // per-wave argmin scratch: [16] min-sc, [16] min-e
    int tid = threadIdx.x;
    for (int j = tid; j < 6400; j += 256) lds[j] = tabs[j];
    for (int j = tid; j < 1024; j += 256) lds[6400 + j] = emb_edge[j];
    for (int j = tid; j < 2048; j += 256) lds[7424 + j] = emb_sbv[j];
    __syncthreads();
    int step = step_ptr[0];
    float invTau;
    if (step == -1) invTau = 1.0f;
    else { float frac = fminf((float)step / 10000.f, 1.f); invTau = 1.0f / (3.0f + (0.1f - 3.0f) * frac); }
    int wid = tid >> 6, lane = tid & 63;
    unsigned* mySc = scr[wid];
    unsigned* myE  = scr[wid] + 16;
    int q = lane >> 4, cidx = (lane & 15) << 2;
    for (int i = blockIdx.x * 4 + wid; i < NN; i += AGG_BLOCKS * 4) {
        unsigned j0 = base[i], j1 = base[i + 1];
        int d = (int)(j1 - j0);
        int r1 = rowArr[i];
        const float* Arow = lds + T_A + r1 * 32;
        const float* Brow = lds + T_B + r1 * 32;
        float4 acc = {0.f, 0.f, 0.f, 0.f};
        if (lane < 16) { mySc[lane] = 0xffffffffu; myE[lane] = 0xffffffffu; }
        __builtin_amdgcn_sched_barrier(0);
        if (d > 0 && d <= 64) {
            // ---- register fast path ----
            bool act = lane < d;
            uint2 key = act ? sKey[j0 + lane] : make_uint2(0u, 0u);
            float sc  = act ? sScal[j0 + lane] : 0.f;
            unsigned scs = sortable_f32(sc);
            unsigned g = key.y & 15u;
            unsigned e19 = key.x & 0x7ffffu;
            if (act) atomicMin(&mySc[g], scs);
            __builtin_amdgcn_sched_barrier(0);
            unsigned ms = mySc[g];
            if (act && scs == ms) atomicMin(&myE[g], e19);
            __builtin_amdgcn_sched_barrier(0);
            bool win = act && (myE[g] == e19);
            int r0 = (key.x >> 19) & 31;
            int ekrow = ((int)(key.y & 15u) << 1) + (win ? 1 : 0);
            float ex = act ? __expf((Arow[r0] + Brow[ekrow]) * invTau) : 0.f;
            float s = ex;
            #pragma unroll
            for (int o = 1; o < 64; o <<= 1) s += __shfl_xor(s, o);
            float p = ex / s;
            int nIt = (d + 3) >> 2;
            for (int it = 0; it < nIt; ++it) {
                int jj = it * 4 + q;
                unsigned kx = __shfl(key.x, jj);
                unsigned ky = (unsigned)__shfl((int)key.y, jj);
                float pp = __shfl(p, jj);
                if (jj < d) {
                    unsigned e = kx & 0x7ffffu;
                    int rr0 = (kx >> 19) & 31, es = (kx >> 24) & 15, esr = (kx >> 28) & 15;
                    int si = (ky >> 4) & 3;
                    float4 tv = *(const float4*)&lds[(rr0 << 6) + cidx];
                    float4 c1 = *(const float4*)&lds[T_C1 + (es << 6) + cidx];
                    float4 c2 = *(const float4*)&lds[T_C2 + (esr << 6) + cidx];
                    float4 c3 = *(const float4*)&lds[T_C3 + (si << 6) + cidx];
                    float4 ee = *(const float4*)&lds[6400 + (es << 6) + cidx];
                    float4 o;
                    o.x = pp * (tv.x + c1.x + c2.x + c3.x);
                    o.y = pp * (tv.y + c1.y + c2.y + c3.y);
                    o.z = pp * (tv.z + c1.z + c2.z + c3.z);
                    o.w = pp * (tv.w + c1.w + c2.w + c3.w);
                    acc.x += o.x; acc.y += o.y; acc.z += o.z; acc.w += o.w;
                    o.x += ee.x; o.y += ee.y; o.z += ee.z; o.w += ee.w;
                    *(float4*)&out_edge[(size_t)e * 64 + cidx] = o;
                }
            }
        } else if (d > 64) {
            // ---- chunked general path ----
            for (unsigned c = j0; c < j1; c += 64) {
                unsigned j = c + lane;
                if (j < j1) {
                    uint2 key = sKey[j];
                    atomicMin(&mySc[key.y & 15u], sortable_f32(sScal[j]));
                }
            }
            __builtin_amdgcn_sched_barrier(0);
            for (unsigned c = j0; c < j1; c += 64) {
                unsigned j = c + lane;
                if (j < j1) {
                    uint2 key = sKey[j];
                    unsigned g = key.y & 15u;
                    if (sortable_f32(sScal[j]) == mySc[g]) atomicMin(&myE[g], key.x & 0x7ffffu);
                }
            }
            __builtin_amdgcn_sched_barrier(0);
            float s = 0.f;
            for (unsigned c = j0; c < j1; c += 64) {
                unsigned j = c + lane;
                if (j < j1) {
                    uint2 key = sKey[j];
                    bool win = (myE[key.y & 15u] == (key.x & 0x7ffffu));
                    int r0 = (key.x >> 19) & 31;
                    int ekrow = ((int)(key.y & 15u) << 1) + (win ? 1 : 0);
                    s += __expf((Arow[r0] + Brow[ekrow]) * invTau);
                }
            }
            #pragma unroll
            for (int o = 1; o < 64; o <<= 1) s += __shfl_xor(s, o);
            float invS = 1.f / s;
            for (unsigned c = j0; c < j1; c += 4) {
                unsigned j = c + q;
                if (j < j1) {
                    uint2 key = sKey[j];
                    bool win = (myE[key.y & 15u] == (key.x & 0x7ffffu));
                    int r0 = (key.x >> 19) & 31;
                    int ekrow = ((int)(key.y & 15u) << 1) + (win ? 1 : 0);
                    float pp = __expf((Arow[r0] + Brow[ekrow]) * invTau) * invS;
                    unsigned e = key.x & 0x7ffffu;
                    int es = (key.x >> 24) & 15, esr = (key.x >> 28) & 15, si = (key.y >> 4) & 3;
                    float4 tv = *(const float4*)&lds[(r0 << 6) + cidx];
                    float4 c1 = *(const float4*)&lds[T_C1 + (es << 6) + cidx];
                    float4 c2 = *(const float4*)&lds[T_C2 + (esr << 6) + cidx];
                    float4 c3 = *(const float4*)&lds[T_C3 + (si << 6) + cidx];
                    float4 ee = *(const float4*)&lds[6400 + (es << 6) + cidx];
                    float4 o;
                    o.x = pp * (tv.x + c1.x + c2.x + c3.x);
                    o.y = pp * (tv.y + c1.y + c2.y + c3.y);
                    o.z = pp * (tv.z + c1.z + c2.z + c3.z);
                    o.w = pp * (tv.w + c1.w + c2.w + c3.w);
                    acc.x += o.x; acc.y += o.y; acc.z += o.z; acc.w += o.w;
                    o.x += ee.x; o.y += ee.y; o.z += ee.z; o.w += ee.w;
                    *(float4*)&out_edge[(size_t)e * 64 + cidx] = o;
                }
            }
        }
        // node reduce across quad groups and write
        acc.x += __shfl_xor(acc.x, 16); acc.y += __shfl_xor(acc.y, 16);
        acc.z += __shfl_xor(acc.z, 16); acc.w += __shfl_xor(acc.w, 16);
        acc.x += __shfl_xor(acc.x, 32); acc.y += __shfl_xor(acc.y, 32);
        acc.z += __shfl_xor(acc.z, 32); acc.w += __shfl_xor(acc.w, 32);
        if (lane < 16) {
            float4 nb = *(const float4*)&lds[7424 + (r1 << 6) + cidx];
            float4 o;
            o.x = nb.x + acc.x; o.y = nb.y + acc.y; o.z = nb.z + acc.z; o.w = nb.w + acc.w;
            *(float4*)&out_node[(size_t)i * 64 + cidx] = o;
        }
    }
}

extern "C" void kernel_launch(void* const* d_in, const int* in_sizes, int n_in,
                              void* d_out, int out_size, void* d_ws, size_t ws_size,
                              hipStream_t stream) {
    const int4*  node_states = (const int4*)d_in[0];
    const int4*  edge_states = (const int4*)d_in[1];
    const float* scalars     = (const float*)d_in[2];
    const int*   edge_index  = (const int*)d_in[3];
    const int*   batch_vec   = (const int*)d_in[4];
    const int*   rev_idx     = (const int*)d_in[5];
    const float* emb_edge    = (const float*)d_in[6];
    const float* emb_sbv     = (const float*)d_in[7];
    const float* emb_sbr     = (const float*)d_in[8];
    const float* emb_static  = (const float*)d_in[9];
    const float* Wq  = (const float*)d_in[10];
    const float* Wk  = (const float*)d_in[11];
    const float* Wv  = (const float*)d_in[12];
    const float* Wek = (const float*)d_in[13];
    const float* Wc  = (const float*)d_in[15];
    const int*   step = (const int*)d_in[16];

    const int* ei0 = edge_index;
    const int* ei1 = edge_index + NE;

    char* ws = (char*)d_ws;
    // workspace layout (byte offsets, NON-OVERLAPPING):
    // [0,        120000)   ns i32 NN
    // [120000,   240000)   rowArr i32 NN
    // [240000,   630000)   esi u8 NE
    // [630000,  2190000)   rank u32 NE
    // [2190000, 2310000)   cnt u32 NN
    // [2310080, 2430084)   base u32 NN+1
    // [2430144, 5550144)   sKey uint2 NE
    // [5550144, 7110144)   sScal f32 NE
    // [7110144, 7118336)   nodeSel u64 1024
    // [7118336, 7168512)   tabs f32 12544
    // [7168512, 7168984)   bsum u32 NB
    // [7169024, 7169500)   bbase u32 NB+1
    int*      ns     = (int*)(ws);
    int*      rowArr = (int*)(ws + 120000);
    unsigned char* esi = (unsigned char*)(ws + 240000);
    unsigned* rank   = (unsigned*)(ws + 630000);
    unsigned* cnt    = (unsigned*)(ws + 2190000);
    unsigned* baseA  = (unsigned*)(ws + 2310080);
    uint2*    sKey   = (uint2*)(ws + 2430144);
    float*    sScal  = (float*)(ws + 5550144);
    unsigned long long* nodeSel = (unsigned long long*)(ws + 7110144);
    float*    tabs   = (float*)(ws + 7118336);
    unsigned* bsum   = (unsigned*)(ws + 7168512);
    unsigned* bbase  = (unsigned*)(ws + 7169024);

    float* out_node = (float*)d_out;
    float* out_edge = out_node + (size_t)NN * HH;

    hipMemsetAsync(cnt, 0, NN * 4, stream);
    hipMemsetAsync(nodeSel, 0xFF, 1024 * 8, stream);

    hipLaunchKernelGGL(k_tab1, dim3(41), dim3(256), 0, stream,
                       emb_sbv, emb_sbr, emb_edge, emb_static, Wq, Wk, Wv, Wek, Wc, tabs);
    hipLaunchKernelGGL(k_tab2, dim3(8), dim3(256), 0, stream, tabs);

    int nb_node = NB;
    int nb_edge = (NE + 255) / 256;

    hipLaunchKernelGGL(k_node1, dim3(nb_node), dim3(256), 0, stream,
                       node_states, scalars, batch_vec, ns, nodeSel);
    hipLaunchKernelGGL(k_edge1, dim3(nb_edge), dim3(256), 0, stream,
                       edge_states, scalars, ei0, ei1, esi, cnt, rank);
    hipLaunchKernelGGL(k_bsum, dim3(NB), dim3(256), 0, stream, cnt, bsum);
    hipLaunchKernelGGL(k_sscan, dim3(1), dim3(128), 0, stream, bsum, bbase, baseA);
    hipLaunchKernelGGL(k_base, dim3(NB), dim3(256), 0, stream,
                       cnt, bbase, baseA, ns, batch_vec, nodeSel, rowArr);
    hipLaunchKernelGGL(k_edge2, dim3(nb_edge), dim3(256), 0, stream,
                       ei0, ei1, rowArr, esi, rev_idx, scalars, baseA, rank, sKey, sScal);
    hipLaunchKernelGGL(k_agg, dim3(AGG_BLOCKS), dim3(256), 0, stream,
                       baseA, sKey, sScal, rowArr, tabs, emb_edge, emb_sbv, step,
                       out_node, out_edge);
}

// Round 7
// 77.375 us; speedup vs baseline: 2.9049x; 1.1997x over previous
//
#include <hip/hip_runtime.h>

#define NN 30000
#define NE 390000
#define HH 64
#define NGRAPH 64
#define AGG_BLOCKS 1024
#define NE_BLK 1524   // ceil(NE/256)
#define NN_BLK 118    // ceil(NN/256)

// ---------- sortable float encoding (ascending order preserved in uint) ----------
__device__ __forceinline__ unsigned sortable_f32(float f) {
    unsigned u = __float_as_uint(f);
    return (u & 0x80000000u) ? ~u : (u | 0x80000000u);
}

// tabs layout (float offsets):
// TV=0 (32x64), TC1=2048 (16x64), TC2=3072 (16x64), TC3=4096 (4x64),
// A=4352 (32x32), B=5376 (32x32), scratch: TQ=6400, TK=8448, TEK=10496
#define T_V   0
#define T_C1  2048
#define T_C2  3072
#define T_C3  4096
#define T_A   4352
#define T_B   5376
#define T_Q   6400
#define T_K   8448
#define T_EK  10496

// D1: esi (es only) + ns + cnt zero + nodeSel init + tab1   [fused, no memsets]
__global__ __launch_bounds__(256) void k_init(
        const int4* __restrict__ edge_states, const int4* __restrict__ node_states,
        const float* __restrict__ emb_sbv, const float* __restrict__ emb_sbr,
        const float* __restrict__ emb_edge, const float* __restrict__ emb_static,
        const float* __restrict__ Wq, const float* __restrict__ Wk,
        const float* __restrict__ Wv, const float* __restrict__ Wek,
        const float* __restrict__ Wc,
        unsigned char* __restrict__ esi, int* __restrict__ ns,
        unsigned* __restrict__ cnt, unsigned long long* __restrict__ nodeSel,
        float* __restrict__ tabs) {
    int b = blockIdx.x, t = threadIdx.x;
    if (b < NE_BLK) {
        int e = b * 256 + t;
        if (e < NE) {
            int4 v = edge_states[e];
            esi[e] = (unsigned char)(v.x + 2*v.y + 4*v.z + 8*v.w);
        }
    } else if (b < NE_BLK + NN_BLK) {
        int i = (b - NE_BLK) * 256 + t;
        if (i < NN) {
            int4 v = node_states[i];
            ns[i] = 2 * (v.x + 2*v.y + 4*v.z + 8*v.w);
            cnt[i] = 0u;
        }
    } else if (b < NE_BLK + NN_BLK + 41) {
        int idx = (b - NE_BLK - NN_BLK) * 256 + t;
        if (idx >= 10496) return;
        float acc = 0.f;
        if (idx < 2048) {              // TV
            int r = idx >> 6, h = idx & 63;
            for (int j = 0; j < 64; ++j) acc += emb_sbv[r*64+j] * Wv[h*64+j];
            tabs[T_V + idx] = acc;
        } else if (idx < 3072) {       // TC1
            int x = idx - 2048; int r = x >> 6, h = x & 63;
            for (int j = 0; j < 64; ++j) acc += emb_edge[r*64+j] * Wc[h*192+j];
            tabs[T_C1 + x] = acc;
        } else if (idx < 4096) {       // TC2
            int x = idx - 3072; int r = x >> 6, h = x & 63;
            for (int j = 0; j < 64; ++j) acc += emb_edge[r*64+j] * Wc[h*192+64+j];
            tabs[T_C2 + x] = acc;
        } else if (idx < 4352) {       // TC3
            int x = idx - 4096; int r = x >> 6, h = x & 63;
            for (int j = 0; j < 64; ++j) acc += emb_static[r*64+j] * Wc[h*192+128+j];
            tabs[T_C3 + x] = acc;
        } else if (idx < 6400) {       // TQ
            int x = idx - 4352; int r = x >> 6, h = x & 63;
            for (int j = 0; j < 64; ++j) acc += emb_sbv[r*64+j] * Wq[h*64+j];
            tabs[T_Q + x] = acc;
        } else if (idx < 8448) {       // TK
            int x = idx - 6400; int r = x >> 6, h = x & 63;
            for (int j = 0; j < 64; ++j) acc += emb_sbv[r*64+j] * Wk[h*64+j];
            tabs[T_K + x] = acc;
        } else {                       // TEK
            int x = idx - 8448; int r = x >> 6, h = x & 63;
            for (int j = 0; j < 64; ++j) acc += emb_sbr[r*64+j] * Wek[h*64+j];
            tabs[T_EK + x] = acc;
        }
    } else {
        // nodeSel init: 256 threads x 4 u64
        #pragma unroll
        for (int k = 0; k < 4; ++k) nodeSel[t * 4 + k] = ~0ull;
    }
}

// D2: rank histogram + node argmin + tab2
__global__ __launch_bounds__(256) void k_phase2(
        const int* __restrict__ ei1, unsigned* __restrict__ cnt,
        unsigned* __restrict__ rank, const int* __restrict__ ns,
        const int* __restrict__ batch_vec, const float* __restrict__ scalars,
        unsigned long long* __restrict__ nodeSel, float* __restrict__ tabs) {
    int b = blockIdx.x, t = threadIdx.x;
    if (b < NE_BLK) {
        int e = b * 256 + t;
        if (e < NE) rank[e] = atomicAdd(&cnt[ei1[e]], 1u);
    } else if (b < NE_BLK + NN_BLK) {
        int i = (b - NE_BLK) * 256 + t;
        if (i < NN) {
            int st = ns[i];
            int key = (st >> 1) * NGRAPH + batch_vec[i];
            unsigned long long pk = ((unsigned long long)sortable_f32(scalars[i]) << 32) | (unsigned)i;
            atomicMin(&nodeSel[key], pk);
        }
    } else {
        int idx = (b - NE_BLK - NN_BLK) * 256 + t;
        if (idx >= 2048) return;
        const float* TQ = tabs + T_Q;
        float acc = 0.f;
        if (idx < 1024) {
            int r1 = idx >> 5, r0 = idx & 31;
            const float* TK = tabs + T_K;
            for (int j = 0; j < 64; ++j) acc += TQ[r1*64+j] * TK[r0*64+j];
            tabs[T_A + idx] = acc * 0.125f;
        } else {
            int x = idx - 1024; int r1 = x >> 5, rk = x & 31;
            const float* TEK = tabs + T_EK;
            for (int j = 0; j < 64; ++j) acc += TQ[r1*64+j] * TEK[rk*64+j];
            tabs[T_B + x] = acc * 0.125f;
        }
    }
}

// D3: block sums of cnt + nodePk build {row, scalar-bits}
__global__ __launch_bounds__(256) void k_phase3(
        const unsigned* __restrict__ cnt, unsigned* __restrict__ bsum,
        const int* __restrict__ ns, const int* __restrict__ batch_vec,
        const unsigned long long* __restrict__ nodeSel,
        const float* __restrict__ scalars, uint2* __restrict__ nodePk) {
    int b = blockIdx.x, t = threadIdx.x;
    if (b < NN_BLK) {
        __shared__ unsigned red[256];
        int i = b * 256 + t;
        red[t] = (i < NN) ? cnt[i] : 0u;
        __syncthreads();
        for (int o = 128; o > 0; o >>= 1) {
            if (t < o) red[t] += red[t + o];
            __syncthreads();
        }
        if (t == 0) bsum[b] = red[0];
    } else {
        int i = (b - NN_BLK) * 256 + t;
        if (i < NN) {
            int st = ns[i];
            int key = (st >> 1) * NGRAPH + batch_vec[i];
            unsigned win = (unsigned)(nodeSel[key] & 0xffffffffull);
            unsigned row = (unsigned)st + (win == (unsigned)i ? 1u : 0u);
            nodePk[i] = make_uint2(row, __float_as_uint(scalars[i]));
        }
    }
}

// D4: scan of 118 block sums
__global__ __launch_bounds__(128) void k_sscan(const unsigned* __restrict__ bsum,
                                               unsigned* __restrict__ bbase,
                                               unsigned* __restrict__ base) {
    __shared__ unsigned s[128];
    int t = threadIdx.x;
    unsigned v = (t < NN_BLK) ? bsum[t] : 0u;
    s[t] = v;
    __syncthreads();
    for (int o = 1; o < 128; o <<= 1) {
        unsigned u = (t >= o) ? s[t - o] : 0u;
        __syncthreads();
        s[t] += u;
        __syncthreads();
    }
    if (t < NN_BLK) bbase[t] = s[t] - v;
    if (t == 127) { bbase[NN_BLK] = s[127]; base[NN] = s[127]; }
}

// D5: per-block scan -> base
__global__ __launch_bounds__(256) void k_base(const unsigned* __restrict__ cnt,
        const unsigned* __restrict__ bbase, unsigned* __restrict__ base) {
    __shared__ unsigned s[256];
    int t = threadIdx.x;
    int i = blockIdx.x * 256 + t;
    unsigned v = (i < NN) ? cnt[i] : 0u;
    s[t] = v;
    __syncthreads();
    for (int o = 1; o < 256; o <<= 1) {
        unsigned u = (t >= o) ? s[t - o] : 0u;
        __syncthreads();
        s[t] += u;
        __syncthreads();
    }
    if (i < NN) base[i] = bbase[blockIdx.x] + s[t] - v;
}

// D6: pack payload, scatter to CSR slot — no atomics
// key.x = e(19) | r0w(5)<<19 | es(4)<<24 | esr(4)<<28 ; key.y = sender-scalar bits
__global__ __launch_bounds__(256) void k_edge2(const int* __restrict__ ei0,
        const int* __restrict__ ei1, const uint2* __restrict__ nodePk,
        const unsigned char* __restrict__ esi, const int* __restrict__ rev_idx,
        const float* __restrict__ scalars, const unsigned* __restrict__ base,
        const unsigned* __restrict__ rank, uint2* __restrict__ sKey,
        float* __restrict__ sScal) {
    int e = blockIdx.x * 256 + threadIdx.x;
    if (e >= NE) return;
    int s0 = ei0[e], s1 = ei1[e];
    uint2 np = nodePk[s0];                        // {row, sender scalar}
    unsigned es = esi[e];
    unsigned esr = esi[rev_idx[e]];
    unsigned pos = base[s1] + rank[e];
    sKey[pos] = make_uint2((unsigned)e | (np.x << 19) | (es << 24) | (esr << 28), np.y);
    sScal[pos] = scalars[e];
}

// D7: one wave per node — in-wave argmin, softmax, si computed here (recv uniform),
// quad-parallel messages. Writes edge_out + node_out. Zero global atomics.
__global__ __launch_bounds__(256) void k_agg(
        const unsigned* __restrict__ base, const uint2* __restrict__ sKey,
        const float* __restrict__ sScal, const uint2* __restrict__ nodePk,
        const float* __restrict__ tabs, const float* __restrict__ emb_edge,
        const float* __restrict__ emb_sbv, const int* __restrict__ step_ptr,
        float* __restrict__ out_node, float* __restrict__ out_edge) {
    // LDS: [0,6400) tabs (TV,TC1,TC2,TC3,A,B); [6400,7424) emb_edge; [7424,9472) emb_sbv
    __shared__ float lds[9472];
    __shared__ unsigned scr[4][32];   // per-wave argmin scratch: [16] min-sc, [16] min-e
    int tid = threadIdx.x;
    for (int j = tid; j < 6400; j += 256) lds[j] = tabs[j];
    for (int j = tid; j < 1024; j += 256) lds[6400 + j] = emb_edge[j];
    for (int j = tid; j < 2048; j += 256) lds[7424 + j] = emb_sbv[j];
    __syncthreads();
    int step = step_ptr[0];
    float invTau;
    if (step == -1) invTau = 1.0f;
    else { float frac = fminf((float)step / 10000.f, 1.f); invTau = 1.0f / (3.0f + (0.1f - 3.0f) * frac); }
    int wid = tid >> 6, lane = tid & 63;
    unsigned* mySc = scr[wid];
    unsigned* myE  = scr[wid] + 16;
    int q = lane >> 4, cidx = (lane & 15) << 2;
    for (int i = blockIdx.x * 4 + wid; i < NN; i += AGG_BLOCKS * 4) {
        unsigned j0 = base[i], j1 = base[i + 1];
        int d = (int)(j1 - j0);
        uint2 np = nodePk[i];
        int r1 = (int)np.x;
        float recv = __uint_as_float(np.y);
        const float* Arow = lds + T_A + r1 * 32;
        const float* Brow = lds + T_B + r1 * 32;
        float4 acc = {0.f, 0.f, 0.f, 0.f};
        if (lane < 16) { mySc[lane] = 0xffffffffu; myE[lane] = 0xffffffffu; }
        __builtin_amdgcn_sched_barrier(0);
        if (d > 0 && d <= 64) {
            // ---- register fast path ----
            bool act = lane < d;
            uint2 key = act ? sKey[j0 + lane] : make_uint2(0u, 0u);
            float sc  = act ? sScal[j0 + lane] : 0.f;
            unsigned scs = sortable_f32(sc);
            unsigned g = (key.x >> 20) & 15u;
            unsigned e19 = key.x & 0x7ffffu;
            if (act) atomicMin(&mySc[g], scs);
            __builtin_amdgcn_sched_barrier(0);
            unsigned ms = mySc[g];
            if (act && scs == ms) atomicMin(&myE[g], e19);
            __builtin_amdgcn_sched_barrier(0);
            bool win = act && (myE[g] == e19);
            int r0 = (key.x >> 19) & 31;
            int ekrow = (r0 & 30) + (win ? 1 : 0);
            float ex = act ? __expf((Arow[r0] + Brow[ekrow]) * invTau) : 0.f;
            float send = __uint_as_float(key.y);
            int si = (sc < recv ? 1 : 0) + (send + sc < recv ? 2 : 0);
            float s = ex;
            #pragma unroll
            for (int o = 1; o < 64; o <<= 1) s += __shfl_xor(s, o);
            float p = ex / s;
            int nIt = (d + 3) >> 2;
            for (int it = 0; it < nIt; ++it) {
                int jj = it * 4 + q;
                unsigned kx = __shfl(key.x, jj);
                int sii = __shfl(si, jj);
                float pp = __shfl(p, jj);
                if (jj < d) {
                    unsigned e = kx & 0x7ffffu;
                    int rr0 = (kx >> 19) & 31, es = (kx >> 24) & 15, esr = (kx >> 28) & 15;
                    float4 tv = *(const float4*)&lds[(rr0 << 6) + cidx];
                    float4 c1 = *(const float4*)&lds[T_C1 + (es << 6) + cidx];
                    float4 c2 = *(const float4*)&lds[T_C2 + (esr << 6) + cidx];
                    float4 c3 = *(const float4*)&lds[T_C3 + (sii << 6) + cidx];
                    float4 ee = *(const float4*)&lds[6400 + (es << 6) + cidx];
                    float4 o;
                    o.x = pp * (tv.x + c1.x + c2.x + c3.x);
                    o.y = pp * (tv.y + c1.y + c2.y + c3.y);
                    o.z = pp * (tv.z + c1.z + c2.z + c3.z);
                    o.w = pp * (tv.w + c1.w + c2.w + c3.w);
                    acc.x += o.x; acc.y += o.y; acc.z += o.z; acc.w += o.w;
                    o.x += ee.x; o.y += ee.y; o.z += ee.z; o.w += ee.w;
                    *(float4*)&out_edge[(size_t)e * 64 + cidx] = o;
                }
            }
        } else if (d > 64) {
            // ---- chunked general path ----
            for (unsigned c = j0; c < j1; c += 64) {
                unsigned j = c + lane;
                if (j < j1) {
                    uint2 key = sKey[j];
                    atomicMin(&mySc[(key.x >> 20) & 15u], sortable_f32(sScal[j]));
                }
            }
            __builtin_amdgcn_sched_barrier(0);
            for (unsigned c = j0; c < j1; c += 64) {
                unsigned j = c + lane;
                if (j < j1) {
                    uint2 key = sKey[j];
                    unsigned g = (key.x >> 20) & 15u;
                    if (sortable_f32(sScal[j]) == mySc[g]) atomicMin(&myE[g], key.x & 0x7ffffu);
                }
            }
            __builtin_amdgcn_sched_barrier(0);
            float s = 0.f;
            for (unsigned c = j0; c < j1; c += 64) {
                unsigned j = c + lane;
                if (j < j1) {
                    uint2 key = sKey[j];
                    bool win = (myE[(key.x >> 20) & 15u] == (key.x & 0x7ffffu));
                    int r0 = (key.x >> 19) & 31;
                    int ekrow = (r0 & 30) + (win ? 1 : 0);
                    s += __expf((Arow[r0] + Brow[ekrow]) * invTau);
                }
            }
            #pragma unroll
            for (int o = 1; o < 64; o <<= 1) s += __shfl_xor(s, o);
            float invS = 1.f / s;
            for (unsigned c = j0; c < j1; c += 4) {
                unsigned j = c + q;
                if (j < j1) {
                    uint2 key = sKey[j];
                    float sc = sScal[j];
                    bool win = (myE[(key.x >> 20) & 15u] == (key.x & 0x7ffffu));
                    int r0 = (key.x >> 19) & 31;
                    int ekrow = (r0 & 30) + (win ? 1 : 0);
                    float pp = __expf((Arow[r0] + Brow[ekrow]) * invTau) * invS;
                    float send = __uint_as_float(key.y);
                    int si = (sc < recv ? 1 : 0) + (send + sc < recv ? 2 : 0);
                    unsigned e = key.x & 0x7ffffu;
                    int es = (key.x >> 24) & 15, esr = (key.x >> 28) & 15;
                    float4 tv = *(const float4*)&lds[(r0 << 6) + cidx];
                    float4 c1 = *(const float4*)&lds[T_C1 + (es << 6) + cidx];
                    float4 c2 = *(const float4*)&lds[T_C2 + (esr << 6) + cidx];
                    float4 c3 = *(const float4*)&lds[T_C3 + (si << 6) + cidx];
                    float4 ee = *(const float4*)&lds[6400 + (es << 6) + cidx];
                    float4 o;
                    o.x = pp * (tv.x + c1.x + c2.x + c3.x);
                    o.y = pp * (tv.y + c1.y + c2.y + c3.y);
                    o.z = pp * (tv.z + c1.z + c2.z + c3.z);
                    o.w = pp * (tv.w + c1.w + c2.w + c3.w);
                    acc.x += o.x; acc.y += o.y; acc.z += o.z; acc.w += o.w;
                    o.x += ee.x; o.y += ee.y; o.z += ee.z; o.w += ee.w;
                    *(float4*)&out_edge[(size_t)e * 64 + cidx] = o;
                }
            }
        }
        // node reduce across quad groups and write
        acc.x += __shfl_xor(acc.x, 16); acc.y += __shfl_xor(acc.y, 16);
        acc.z += __shfl_xor(acc.z, 16); acc.w += __shfl_xor(acc.w, 16);
        acc.x += __shfl_xor(acc.x, 32); acc.y += __shfl_xor(acc.y, 32);
        acc.z += __shfl_xor(acc.z, 32); acc.w += __shfl_xor(acc.w, 32);
        if (lane < 16) {
            float4 nb = *(const float4*)&lds[7424 + (r1 << 6) + cidx];
            float4 o;
            o.x = nb.x + acc.x; o.y = nb.y + acc.y; o.z = nb.z + acc.z; o.w = nb.w + acc.w;
            *(float4*)&out_node[(size_t)i * 64 + cidx] = o;
        }
    }
}

extern "C" void kernel_launch(void* const* d_in, const int* in_sizes, int n_in,
                              void* d_out, int out_size, void* d_ws, size_t ws_size,
                              hipStream_t stream) {
    const int4*  node_states = (const int4*)d_in[0];
    const int4*  edge_states = (const int4*)d_in[1];
    const float* scalars     = (const float*)d_in[2];
    const int*   edge_index  = (const int*)d_in[3];
    const int*   batch_vec   = (const int*)d_in[4];
    const int*   rev_idx     = (const int*)d_in[5];
    const float* emb_edge    = (const float*)d_in[6];
    const float* emb_sbv     = (const float*)d_in[7];
    const float* emb_sbr     = (const float*)d_in[8];
    const float* emb_static  = (const float*)d_in[9];
    const float* Wq  = (const float*)d_in[10];
    const float* Wk  = (const float*)d_in[11];
    const float* Wv  = (const float*)d_in[12];
    const float* Wek = (const float*)d_in[13];
    const float* Wc  = (const float*)d_in[15];
    const int*   step = (const int*)d_in[16];

    const int* ei0 = edge_index;
    const int* ei1 = edge_index + NE;

    char* ws = (char*)d_ws;
    // workspace layout (byte offsets, NON-OVERLAPPING):
    // [0,        120000)   ns i32 NN
    // [120000,   360000)   nodePk uint2 NN
    // [360000,   750016)   esi u8 NE (pad)
    // [750016,  2310016)   rank u32 NE
    // [2310016, 2430016)   cnt u32 NN
    // [2430080, 2550084)   base u32 NN+1
    // [2550144, 5670144)   sKey uint2 NE
    // [5670144, 7230144)   sScal f32 NE
    // [7230144, 7238336)   nodeSel u64 1024
    // [7238336, 7288512)   tabs f32 12544
    // [7288512, 7288984)   bsum u32 NN_BLK
    // [7289024, 7289504)   bbase u32 NN_BLK+1
    int*      ns     = (int*)(ws);
    uint2*    nodePk = (uint2*)(ws + 120000);
    unsigned char* esi = (unsigned char*)(ws + 360000);
    unsigned* rank   = (unsigned*)(ws + 750016);
    unsigned* cnt    = (unsigned*)(ws + 2310016);
    unsigned* baseA  = (unsigned*)(ws + 2430080);
    uint2*    sKey   = (uint2*)(ws + 2550144);
    float*    sScal  = (float*)(ws + 5670144);
    unsigned long long* nodeSel = (unsigned long long*)(ws + 7230144);
    float*    tabs   = (float*)(ws + 7238336);
    unsigned* bsum   = (unsigned*)(ws + 7288512);
    unsigned* bbase  = (unsigned*)(ws + 7289024);

    float* out_node = (float*)d_out;
    float* out_edge = out_node + (size_t)NN * HH;

    hipLaunchKernelGGL(k_init, dim3(NE_BLK + NN_BLK + 41 + 1), dim3(256), 0, stream,
                       edge_states, node_states, emb_sbv, emb_sbr, emb_edge, emb_static,
                       Wq, Wk, Wv, Wek, Wc, esi, ns, cnt, nodeSel, tabs);
    hipLaunchKernelGGL(k_phase2, dim3(NE_BLK + NN_BLK + 8), dim3(256), 0, stream,
                       ei1, cnt, rank, ns, batch_vec, scalars, nodeSel, tabs);
    hipLaunchKernelGGL(k_phase3, dim3(NN_BLK * 2), dim3(256), 0, stream,
                       cnt, bsum, ns, batch_vec, nodeSel, scalars, nodePk);
    hipLaunchKernelGGL(k_sscan, dim3(1), dim3(128), 0, stream, bsum, bbase, baseA);
    hipLaunchKernelGGL(k_base, dim3(NN_BLK), dim3(256), 0, stream, cnt, bbase, baseA);
    hipLaunchKernelGGL(k_edge2, dim3(NE_BLK), dim3(256), 0, stream,
                       ei0, ei1, nodePk, esi, rev_idx, scalars, baseA, rank, sKey, sScal);
    hipLaunchKernelGGL(k_agg, dim3(AGG_BLOCKS), dim3(256), 0, stream,
                       baseA, sKey, sScal, nodePk, tabs, emb_edge, emb_sbv, step,
                       out_node, out_edge);
}